// Round 2
// baseline (3501.714 us; speedup 1.0000x reference)
//
#include <hip/hip_runtime.h>
#include <hip/hip_bf16.h>
#include <cstdint>
#include <math.h>

typedef __bf16 bf16_t;
typedef bf16_t bf16x8 __attribute__((ext_vector_type(8)));
typedef float f32x4 __attribute__((ext_vector_type(4)));

#define B_ 32
#define T_ 2048
#define D_ 256
#define INNER_ 512
#define L_ 3
#define CHUNK_ 64
#define NCHUNK_ (T_/CHUNK_) // 32

struct GemmP {
  const bf16_t* A;
  const bf16_t* Bt;
  const float* bias;
  float* outF;
  bf16_t* outB;
  const int* day_ids;   // already offset by group base batch
  long bStrideBt;
  int bStrideBias;
  int K, N, ldout, colOff, act, revA, revC, nValid;
};

// ---------------- GEMM: C = A(MxK) * Bt(NxK)^T, bf16 in, fp32 acc ----------------
__global__ __launch_bounds__(256, 2)
void gemm_kernel(GemmP p) {
  __shared__ bf16_t As[128][32];
  __shared__ bf16_t Bs[128][32];
  const int tid = threadIdx.x;
  const int wave = tid >> 6, lane = tid & 63;
  const int m0 = blockIdx.x << 7, n0 = blockIdx.y << 7;
  const bf16_t* Bt = p.Bt;
  const float* bias = p.bias;
  if (p.day_ids) {
    int day = p.day_ids[m0 >> 11];      // 2048 rows per batch
    Bt += (long)day * p.bStrideBt;
    if (bias) bias += (long)day * p.bStrideBias;
  }
  const int K = p.K;
  const int srow = tid >> 2;        // 0..63
  const int sk = (tid & 3) << 3;    // 0,8,16,24

  int ar0 = m0 + srow, ar1 = m0 + srow + 64;
  if (p.revA) {
    int t0 = ar0 & (T_-1); ar0 = ar0 - t0 + (T_-1 - t0);
    int t1 = ar1 & (T_-1); ar1 = ar1 - t1 + (T_-1 - t1);
  }
  const bf16_t* aP0 = p.A + (long)ar0 * K + sk;
  const bf16_t* aP1 = p.A + (long)ar1 * K + sk;
  const bf16_t* bP0 = Bt + (long)(n0 + srow) * K + sk;
  const bf16_t* bP1 = bP0 + (long)64 * K;

  f32x4 acc[4][4] = {};
  const int mw = ((wave >> 1) << 6), nw = ((wave & 1) << 6);
  const int fr = lane & 15;
  const int fk = (lane >> 4) << 3;

  for (int k0 = 0; k0 < K; k0 += 32) {
    *(bf16x8*)&As[srow][sk]      = *(const bf16x8*)(aP0 + k0);
    *(bf16x8*)&As[srow + 64][sk] = *(const bf16x8*)(aP1 + k0);
    *(bf16x8*)&Bs[srow][sk]      = *(const bf16x8*)(bP0 + k0);
    *(bf16x8*)&Bs[srow + 64][sk] = *(const bf16x8*)(bP1 + k0);
    __syncthreads();
    bf16x8 af[4], bfr[4];
#pragma unroll
    for (int i = 0; i < 4; i++) af[i] = *(const bf16x8*)&As[mw + i*16 + fr][fk];
#pragma unroll
    for (int j = 0; j < 4; j++) bfr[j] = *(const bf16x8*)&Bs[nw + j*16 + fr][fk];
#pragma unroll
    for (int i = 0; i < 4; i++)
#pragma unroll
      for (int j = 0; j < 4; j++)
        acc[i][j] = __builtin_amdgcn_mfma_f32_16x16x32_bf16(af[i], bfr[j], acc[i][j], 0, 0, 0);
    __syncthreads();
  }

  const int cn = lane & 15, rq = (lane >> 4) << 2;
#pragma unroll
  for (int i = 0; i < 4; i++) {
#pragma unroll
    for (int r = 0; r < 4; r++) {
      int gr = m0 + mw + i*16 + rq + r;
      int orow = gr;
      if (p.revC) { int t = gr & (T_-1); orow = gr - t + (T_-1 - t); }
      long rowOff = (long)orow * p.ldout + p.colOff;
#pragma unroll
      for (int j = 0; j < 4; j++) {
        int col = n0 + nw + j*16 + cn;
        if (col >= p.nValid) continue;
        float v = acc[i][j][r];
        if (bias) v += bias[col];
        if (p.act == 1) v = v / (1.f + fabsf(v));                       // softsign
        else if (p.act == 2) v = (v > 20.f) ? v : log1pf(expf(v));      // softplus
        if (p.outF) p.outF[rowOff + col] = v;
        if (p.outB) p.outB[rowOff + col] = (bf16_t)v;
      }
    }
  }
}

// ---------------- LayerNorm (one wave per 256-wide row) --------------------------
// in: fp32; optional bf16 residual; optional silu; bf16 out
__global__ __launch_bounds__(256)
void ln_kernel(const float* in, const bf16_t* resid, const float* s, const float* bb,
               bf16_t* outB, int doSilu) {
  int row = (blockIdx.x << 2) + (threadIdx.x >> 6);
  int lane = threadIdx.x & 63;
  long base = (long)row * D_ + (lane << 2);
  f32x4 v = *(const f32x4*)(in + base);
  if (resid) {
#pragma unroll
    for (int k = 0; k < 4; k++) v[k] += (float)resid[base + k];
  }
  float s1 = v[0] + v[1] + v[2] + v[3];
  float s2 = v[0]*v[0] + v[1]*v[1] + v[2]*v[2] + v[3]*v[3];
#pragma unroll
  for (int off = 1; off < 64; off <<= 1) {
    s1 += __shfl_xor(s1, off);
    s2 += __shfl_xor(s2, off);
  }
  float mean = s1 * (1.f / D_);
  float var = s2 * (1.f / D_) - mean * mean;
  float inv = rsqrtf(var + 1e-5f);
  f32x4 sv = *(const f32x4*)(s + (lane << 2));
  f32x4 bv = *(const f32x4*)(bb + (lane << 2));
#pragma unroll
  for (int k = 0; k < 4; k++) {
    float val = (v[k] - mean) * inv * sv[k] + bv[k];
    if (doSilu) val = val / (1.f + expf(-val));
    outB[base + k] = (bf16_t)val;
  }
}

// ---------------- depthwise conv (taps t-2..t+1) + bias + silu -------------------
__global__ void conv_kernel(const bf16_t* xz, const float* K4, const float* cb, bf16_t* xc) {
  long idx = ((long)blockIdx.x * blockDim.x + threadIdx.x);
  int ch = (int)(idx & (INNER_-1));
  long bt = idx >> 9;
  int t = (int)(bt & (T_-1));
  long base = bt * (2*INNER_) + ch;
  f32x4 kk = *(const f32x4*)(K4 + (ch << 2));
  float acc = cb[ch];
  if (t >= 2) acc += (float)xz[base - 2*(2*INNER_)] * kk[0];
  if (t >= 1) acc += (float)xz[base - (2*INNER_)] * kk[1];
  acc += (float)xz[base] * kk[2];
  if (t < T_-1) acc += (float)xz[base + (2*INNER_)] * kk[3];
  float sv = acc / (1.f + expf(-acc));
  xc[bt * INNER_ + ch] = (bf16_t)sv;
}

// ---------------- chunked scan for w = exp(-0.1*cumsum(dt)) ----------------------
__global__ void chunksum_kernel(const bf16_t* dt, float* sums) {
  int bc = blockIdx.x;
  int ch = threadIdx.x;
  long base = (long)bc * CHUNK_ * INNER_ + ch;
  float s = 0.f;
  for (int i = 0; i < CHUNK_; i++) s += (float)dt[base + (long)i * INNER_];
  sums[(long)bc * INNER_ + ch] = s;
}

__global__ void scan_kernel(float* sums) {
  int b = blockIdx.x, ch = threadIdx.x;
  float run = 0.f;
  for (int c = 0; c < NCHUNK_; c++) {
    long i = ((long)b * NCHUNK_ + c) * INNER_ + ch;
    float v = sums[i];
    sums[i] = run;
    run += v;
  }
}

// y = xc * w * silu(z), written IN PLACE over xc
__global__ void y_kernel(const bf16_t* dt, const bf16_t* xz, bf16_t* xc,
                         const float* sums) {
  int bc = blockIdx.x, ch = threadIdx.x;
  float acc = sums[(long)bc * INNER_ + ch];
  long bt0 = (long)bc * CHUNK_;
  for (int i = 0; i < CHUNK_; i++) {
    long bt = bt0 + i;
    long i512 = bt * INNER_ + ch;
    acc += (float)dt[i512];
    float w = expf(-0.1f * acc);
    float zz = (float)xz[bt * (2*INNER_) + INNER_ + ch];
    float sz = zz / (1.f + expf(-zz));
    xc[i512] = (bf16_t)((float)xc[i512] * w * sz);
  }
}

// ---------------- log_softmax over 41 (one wave per row) -------------------------
__global__ __launch_bounds__(256)
void lsm_kernel(const float* logits, float* out) {
  int row = (blockIdx.x << 2) + (threadIdx.x >> 6);
  int lane = threadIdx.x & 63;
  float v = (lane < 41) ? logits[(long)row * 41 + lane] : -3.4e38f;
  float m = v;
#pragma unroll
  for (int off = 1; off < 64; off <<= 1) m = fmaxf(m, __shfl_xor(m, off));
  float e = (lane < 41) ? expf(v - m) : 0.f;
  float ssum = e;
#pragma unroll
  for (int off = 1; off < 64; off <<= 1) ssum += __shfl_xor(ssum, off);
  float ls = logf(ssum);
  if (lane < 41) out[(long)row * 41 + lane] = v - m - ls;
}

// ---------------- fp32 (R,C) -> bf16 (C,R) transpose, batched via z --------------
__global__ void tconv_kernel(const float* in, bf16_t* out, int R, int C) {
  __shared__ float tile[32][33];
  const float* ip = in + (long)blockIdx.z * R * C;
  bf16_t* op = out + (long)blockIdx.z * R * C;
  int c0 = blockIdx.x << 5, r0 = blockIdx.y << 5;
  int tx = threadIdx.x, ty = threadIdx.y;
  for (int i = ty; i < 32; i += 8) {
    int r = r0 + i, c = c0 + tx;
    tile[i][tx] = (r < R && c < C) ? ip[(long)r * C + c] : 0.f;
  }
  __syncthreads();
  for (int i = ty; i < 32; i += 8) {
    int c = c0 + i, r = r0 + tx;
    if (c < C && r < R) op[(long)c * R + r] = (bf16_t)tile[tx][i];
  }
}

__global__ void cvt_kernel(const float* in, bf16_t* out, long n) {
  long i = ((long)blockIdx.x * blockDim.x + threadIdx.x) << 2;
  if (i >= n) return;
  f32x4 v = *(const f32x4*)(in + i);
  out[i]   = (bf16_t)v[0];
  out[i+1] = (bf16_t)v[1];
  out[i+2] = (bf16_t)v[2];
  out[i+3] = (bf16_t)v[3];
}

__global__ void zfill_kernel(bf16_t* p, int n) {
  int i = blockIdx.x * 256 + threadIdx.x;
  if (i < n) p[i] = (bf16_t)0.f;
}

extern "C" void kernel_launch(void* const* d_in, const int* in_sizes, int n_in,
                              void* d_out, int out_size, void* d_ws, size_t ws_size,
                              hipStream_t stream) {
  (void)in_sizes; (void)n_in; (void)out_size;
  const float* x         = (const float*)d_in[0];
  const int*   day_ids   = (const int*)d_in[1];
  const float* adapter_W = (const float*)d_in[2];
  const float* adapter_b = (const float*)d_in[3];
  const float* cW1       = (const float*)d_in[4];
  const float* cb1       = (const float*)d_in[5];
  const float* cln1_s    = (const float*)d_in[6];
  const float* cln1_b    = (const float*)d_in[7];
  const float* cW2       = (const float*)d_in[8];
  const float* cb2       = (const float*)d_in[9];
  const float* cln2_s    = (const float*)d_in[10];
  const float* cln2_b    = (const float*)d_in[11];
  const float* m_in      = (const float*)d_in[12];
  const float* m_convK   = (const float*)d_in[13];
  const float* m_convB   = (const float*)d_in[14];
  const float* m_dtW     = (const float*)d_in[15];
  const float* m_dtB     = (const float*)d_in[16];
  const float* m_out     = (const float*)d_in[17];
  const float* proj_W    = (const float*)d_in[18];
  const float* proj_b    = (const float*)d_in[19];
  const float* norm_s    = (const float*)d_in[20];
  const float* norm_b    = (const float*)d_in[21];
  const float* outW      = (const float*)d_in[22];
  const float* outb      = (const float*)d_in[23];
  float* out = (float*)d_out;

  char* ws = (char*)d_ws;
  size_t off = 0;
  auto alloc = [&](size_t bytes) -> char* {
    char* p = ws + off;
    off += (bytes + 255) & ~(size_t)255;
    return p;
  };
  // ---- fixed: transposed bf16 weights (~33 MB) ----
  bf16_t* adapterT = (bf16_t*)alloc((size_t)45*512*512*2);
  bf16_t* cW1T     = (bf16_t*)alloc((size_t)256*512*2);
  bf16_t* cW2T     = (bf16_t*)alloc((size_t)256*256*2);
  bf16_t* m_inT    = (bf16_t*)alloc((size_t)6*1024*256*2);
  bf16_t* m_dtWT   = (bf16_t*)alloc((size_t)6*512*512*2);
  bf16_t* m_outT   = (bf16_t*)alloc((size_t)6*256*512*2);
  bf16_t* projT    = (bf16_t*)alloc((size_t)3*256*512*2);
  bf16_t* outWT    = (bf16_t*)alloc((size_t)128*256*2);

  // ---- adaptive group size: largest Bg whose regions fit ws_size ----
  int Bg = 0;
  {
    const int cands[6] = {32, 16, 8, 4, 2, 1};
    for (int ci = 0; ci < 6; ci++) {
      int c = cands[ci];
      size_t Mg = (size_t)c * T_;
      size_t need = Mg*2048 + 3*(Mg*1024) + Mg*512 + (size_t)c*NCHUNK_*INNER_*4
                    + 8*256;  // alignment slack
      if (off + need <= ws_size) { Bg = c; break; }
    }
  }
  if (Bg == 0) return;  // workspace too small to run at all
  const size_t Mg = (size_t)Bg * T_;
  char*  xzR  = alloc(Mg * 2048);          // xz (Mg x 1024 bf16); also x_bf, logits
  char*  xcR  = alloc(Mg * 1024);          // xc / y (Mg x 512 bf16); also h0
  char*  dtR  = alloc(Mg * 1024);          // dt (Mg x 512 bf16); also tmpF (Mg x 256 f32)
  char*  swR  = alloc(Mg * 1024);          // swcat (Mg x 512 bf16); also h1
  bf16_t* hG  = (bf16_t*)alloc(Mg * 512);  // h (Mg x 256 bf16)
  float* sums = (float*)alloc((size_t)Bg * NCHUNK_ * INNER_ * 4);

  // ---- weight conversion/transpose (once) ----
  zfill_kernel<<<128, 256, 0, stream>>>(outWT, 128*256);
  dim3 tb(32, 8);
  tconv_kernel<<<dim3(16,16,45), tb, 0, stream>>>(adapter_W, adapterT, 512, 512);
  tconv_kernel<<<dim3(8,16,1),  tb, 0, stream>>>(cW1,  cW1T,  512, 256);
  tconv_kernel<<<dim3(8,8,1),   tb, 0, stream>>>(cW2,  cW2T,  256, 256);
  tconv_kernel<<<dim3(32,8,6),  tb, 0, stream>>>(m_in, m_inT, 256, 1024);
  tconv_kernel<<<dim3(16,16,6), tb, 0, stream>>>(m_dtW, m_dtWT, 512, 512);
  tconv_kernel<<<dim3(8,16,6),  tb, 0, stream>>>(m_out, m_outT, 512, 256);
  tconv_kernel<<<dim3(8,16,3),  tb, 0, stream>>>(proj_W, projT, 512, 256);
  tconv_kernel<<<dim3(2,8,1),   tb, 0, stream>>>(outW, outWT, 256, 41);

  auto gemm = [&](const bf16_t* A, const bf16_t* Bt, const float* bias,
                  float* outF, bf16_t* outB, int K, int N, int ldout, int colOff,
                  int act, int revA, int revC, const int* days, long bsBt, int bsBias,
                  int nValid) {
    GemmP p;
    p.A = A; p.Bt = Bt; p.bias = bias; p.outF = outF; p.outB = outB;
    p.day_ids = days; p.bStrideBt = bsBt; p.bStrideBias = bsBias;
    p.K = K; p.N = N; p.ldout = ldout; p.colOff = colOff;
    p.act = act; p.revA = revA; p.revC = revC; p.nValid = nValid;
    gemm_kernel<<<dim3((unsigned)(Mg/128), N/128), 256, 0, stream>>>(p);
  };

  for (int b0 = 0; b0 < B_; b0 += Bg) {
    const float* xg = x + (size_t)b0 * T_ * 512;

    // ---- x -> bf16 ----
    bf16_t* x_bf = (bf16_t*)xzR;
    cvt_kernel<<<(unsigned)(Mg/2), 256, 0, stream>>>(xg, x_bf, (long)Mg*512);

    // ---- adapter: h0 = softsign(x @ W[day] + b[day]) ----
    bf16_t* h0 = (bf16_t*)xcR;
    gemm(x_bf, adapterT, adapter_b, nullptr, h0, 512, 512, 512, 0, /*act*/1, 0, 0,
         day_ids + b0, (long)512*512, 512, 512);

    // ---- h1 = silu(LN(h0 @ cW1 + cb1)) ----
    float* tmpF = (float*)dtR;
    gemm(h0, cW1T, cb1, tmpF, nullptr, 512, 256, 256, 0, 0, 0, 0, nullptr, 0, 0, 256);
    bf16_t* h1 = (bf16_t*)swR;
    ln_kernel<<<(unsigned)(Mg/4), 256, 0, stream>>>(tmpF, nullptr, cln1_s, cln1_b, h1, 1);

    // ---- h = silu(LN(h1 @ cW2 + cb2)) ----
    gemm(h1, cW2T, cb2, tmpF, nullptr, 256, 256, 256, 0, 0, 0, 0, nullptr, 0, 0, 256);
    ln_kernel<<<(unsigned)(Mg/4), 256, 0, stream>>>(tmpF, nullptr, cln2_s, cln2_b, hG, 1);

    bf16_t* xz    = (bf16_t*)xzR;
    bf16_t* xc    = (bf16_t*)xcR;
    bf16_t* dt    = (bf16_t*)dtR;
    bf16_t* swcat = (bf16_t*)swR;

    for (int l = 0; l < L_; l++) {
      for (int dir = 0; dir < 2; dir++) {
        int ld = l*2 + dir;
        // xz = h @ Win (reversed read of h for dir=1)
        gemm(hG, m_inT + (size_t)ld*1024*256, nullptr, nullptr, xz,
             256, 1024, 1024, 0, 0, /*revA*/dir, 0, nullptr, 0, 0, 1024);
        // xc = silu(dwconv(xi) + convB)
        conv_kernel<<<(unsigned)(Mg*2), 256, 0, stream>>>(
            xz, m_convK + (size_t)ld*512*4, m_convB + (size_t)ld*512, xc);
        // dt = softplus(xc @ dtW + dtB)
        gemm(xc, m_dtWT + (size_t)ld*512*512, m_dtB + (size_t)ld*512, nullptr, dt,
             512, 512, 512, 0, /*act*/2, 0, 0, nullptr, 0, 0, 512);
        // w = exp(-0.1*cumsum(dt)); y = xc * w * silu(z)   (in place over xc)
        chunksum_kernel<<<Bg*NCHUNK_, INNER_, 0, stream>>>(dt, sums);
        scan_kernel<<<Bg, INNER_, 0, stream>>>(sums);
        y_kernel<<<Bg*NCHUNK_, INNER_, 0, stream>>>(dt, xz, xc, sums);
        // swcat[:, dir*256:...] = y @ Wout (store reversed for dir=1)
        gemm(xc, m_outT + (size_t)ld*256*512, nullptr, nullptr, swcat,
             512, 256, 512, dir*256, 0, 0, /*revC*/dir, nullptr, 0, 0, 256);
      }
      // combined = swcat @ proj_W + proj_b; h = LN(h + combined)
      float* tmpF2 = (float*)dtR;
      gemm(swcat, projT + (size_t)l*256*512, proj_b + (size_t)l*256, tmpF2, nullptr,
           512, 256, 256, 0, 0, 0, 0, nullptr, 0, 0, 256);
      ln_kernel<<<(unsigned)(Mg/4), 256, 0, stream>>>(tmpF2, hG, norm_s + (size_t)l*256,
                                                      norm_b + (size_t)l*256, hG, 0);
    }

    // ---- logits + log_softmax ----
    float* logits = (float*)xzR;
    gemm(hG, outWT, outb, logits, nullptr, 256, 128, 41, 0, 0, 0, 0,
         nullptr, 0, 0, 41);
    lsm_kernel<<<(unsigned)(Mg/4), 256, 0, stream>>>(logits, out + (size_t)b0 * T_ * 41);
  }
}

// Round 3
// 3299.295 us; speedup vs baseline: 1.0614x; 1.0614x over previous
//
#include <hip/hip_runtime.h>
#include <hip/hip_bf16.h>
#include <cstdint>
#include <math.h>

typedef __bf16 bf16_t;
typedef bf16_t bf16x8 __attribute__((ext_vector_type(8)));
typedef float f32x4 __attribute__((ext_vector_type(4)));

#define B_ 32
#define T_ 2048
#define D_ 256
#define INNER_ 512
#define L_ 3
#define CHUNK_ 64
#define NCHUNK_ (T_/CHUNK_) // 32

typedef const __attribute__((address_space(1))) void* gas_t;
typedef __attribute__((address_space(3))) void* las_t;
__device__ __forceinline__ void gll16(const void* g, void* l) {
  __builtin_amdgcn_global_load_lds((gas_t)g, (las_t)l, 16, 0, 0);
}

struct GemmP {
  const bf16_t* A;
  const bf16_t* Bt;
  const float* bias;
  float* outF;
  bf16_t* outB;
  const int* day_ids;   // already offset by group base batch
  long bStrideBt;
  int bStrideBias;
  int K, N, ldout, colOff, act, revA, revC, nValid;
};

// ---------------- GEMM: C = A(MxK) * Bt(NxK)^T, bf16 in, fp32 acc ----------------
// LDS layout swizzle: global 16B chunk (r, c) lives at byte r*64 + (((c + (r>>2))&3)<<4).
// Staging via global_load_lds (lane*16 dest); swizzle applied to the GLOBAL source
// chunk each lane fetches. Fragment reads then hit every bank exactly 2-way (free).
__global__ __launch_bounds__(256, 4)
void gemm_kernel(GemmP p) {
  __shared__ bf16_t As[128*32];
  __shared__ bf16_t Bs[128*32];
  const int tid = threadIdx.x;
  const int wave = tid >> 6, lane = tid & 63;
  const int m0 = blockIdx.x << 7, n0 = blockIdx.y << 7;
  const bf16_t* Bt = p.Bt;
  const float* bias = p.bias;
  if (p.day_ids) {
    int day = p.day_ids[m0 >> 11];      // 2048 rows per batch
    Bt += (long)day * p.bStrideBt;
    if (bias) bias += (long)day * p.bStrideBias;
  }
  const int K = p.K;
  const int srow = tid >> 2;                      // 0..63
  const int sc = ((tid & 3) - (tid >> 4)) & 3;    // global chunk this lane stages
  const int sk = sc << 3;                         // element offset of that chunk

  int ar0 = m0 + srow, ar1 = m0 + srow + 64;
  if (p.revA) {
    int t0 = ar0 & (T_-1); ar0 = ar0 - t0 + (T_-1 - t0);
    int t1 = ar1 & (T_-1); ar1 = ar1 - t1 + (T_-1 - t1);
  }
  const bf16_t* aP0 = p.A + (long)ar0 * K + sk;
  const bf16_t* aP1 = p.A + (long)ar1 * K + sk;
  const bf16_t* bP0 = Bt + (long)(n0 + srow) * K + sk;
  const bf16_t* bP1 = bP0 + (long)64 * K;

  char* ldsA0 = (char*)As + wave * 1024;          // rows 0-63   (tid*16)
  char* ldsA1 = (char*)As + 4096 + wave * 1024;   // rows 64-127
  char* ldsB0 = (char*)Bs + wave * 1024;
  char* ldsB1 = (char*)Bs + 4096 + wave * 1024;

  f32x4 acc[4][4] = {};
  const int mw = ((wave >> 1) << 6), nw = ((wave & 1) << 6);
  const int fr = lane & 15;
  const int foff = (((lane >> 4) + (fr >> 2)) & 3) << 4;  // swizzled chunk byte off

  for (int k0 = 0; k0 < K; k0 += 32) {
    gll16(aP0 + k0, ldsA0);
    gll16(aP1 + k0, ldsA1);
    gll16(bP0 + k0, ldsB0);
    gll16(bP1 + k0, ldsB1);
    __syncthreads();
    bf16x8 af[4], bfr[4];
#pragma unroll
    for (int i = 0; i < 4; i++)
      af[i] = *(const bf16x8*)((char*)As + (mw + i*16 + fr)*64 + foff);
#pragma unroll
    for (int j = 0; j < 4; j++)
      bfr[j] = *(const bf16x8*)((char*)Bs + (nw + j*16 + fr)*64 + foff);
#pragma unroll
    for (int i = 0; i < 4; i++)
#pragma unroll
      for (int j = 0; j < 4; j++)
        acc[i][j] = __builtin_amdgcn_mfma_f32_16x16x32_bf16(af[i], bfr[j], acc[i][j], 0, 0, 0);
    __syncthreads();
  }

  const int cn = lane & 15, rq = (lane >> 4) << 2;
#pragma unroll
  for (int i = 0; i < 4; i++) {
#pragma unroll
    for (int r = 0; r < 4; r++) {
      int gr = m0 + mw + i*16 + rq + r;
      int orow = gr;
      if (p.revC) { int t = gr & (T_-1); orow = gr - t + (T_-1 - t); }
      long rowOff = (long)orow * p.ldout + p.colOff;
#pragma unroll
      for (int j = 0; j < 4; j++) {
        int col = n0 + nw + j*16 + cn;
        if (col >= p.nValid) continue;
        float v = acc[i][j][r];
        if (bias) v += bias[col];
        if (p.act == 1) v = v / (1.f + fabsf(v));                       // softsign
        else if (p.act == 2) v = (v > 20.f) ? v : log1pf(expf(v));      // softplus
        if (p.outF) p.outF[rowOff + col] = v;
        if (p.outB) p.outB[rowOff + col] = (bf16_t)v;
      }
    }
  }
}

// ---------------- LayerNorm (one wave per 256-wide row) --------------------------
__global__ __launch_bounds__(256)
void ln_kernel(const float* in, const bf16_t* resid, const float* s, const float* bb,
               bf16_t* outB, int doSilu) {
  int row = (blockIdx.x << 2) + (threadIdx.x >> 6);
  int lane = threadIdx.x & 63;
  long base = (long)row * D_ + (lane << 2);
  f32x4 v = *(const f32x4*)(in + base);
  if (resid) {
#pragma unroll
    for (int k = 0; k < 4; k++) v[k] += (float)resid[base + k];
  }
  float s1 = v[0] + v[1] + v[2] + v[3];
  float s2 = v[0]*v[0] + v[1]*v[1] + v[2]*v[2] + v[3]*v[3];
#pragma unroll
  for (int off = 1; off < 64; off <<= 1) {
    s1 += __shfl_xor(s1, off);
    s2 += __shfl_xor(s2, off);
  }
  float mean = s1 * (1.f / D_);
  float var = s2 * (1.f / D_) - mean * mean;
  float inv = rsqrtf(var + 1e-5f);
  f32x4 sv = *(const f32x4*)(s + (lane << 2));
  f32x4 bv = *(const f32x4*)(bb + (lane << 2));
#pragma unroll
  for (int k = 0; k < 4; k++) {
    float val = (v[k] - mean) * inv * sv[k] + bv[k];
    if (doSilu) val = val / (1.f + expf(-val));
    outB[base + k] = (bf16_t)val;
  }
}

// ---------------- depthwise conv (taps t-2..t+1) + bias + silu, x8 vectorized ----
__global__ __launch_bounds__(256)
void conv_kernel(const bf16_t* xz, const float* K4, const float* cb, bf16_t* xc) {
  long idx = (long)blockIdx.x * 256 + threadIdx.x;
  int ch0 = ((int)(idx & 63)) << 3;
  long bt = idx >> 6;
  int t = (int)(bt & (T_-1));
  const bf16_t* base = xz + bt * (2*INNER_) + ch0;
  bf16x8 r0, r1, r2, r3;
  r2 = *(const bf16x8*)(base);
#pragma unroll
  for (int k = 0; k < 8; k++) { r0[k] = (bf16_t)0.f; r1[k] = (bf16_t)0.f; r3[k] = (bf16_t)0.f; }
  if (t >= 2) r0 = *(const bf16x8*)(base - 2*(2*INNER_));
  if (t >= 1) r1 = *(const bf16x8*)(base - (2*INNER_));
  if (t < T_-1) r3 = *(const bf16x8*)(base + (2*INNER_));
  bf16x8 o8;
#pragma unroll
  for (int k = 0; k < 8; k++) {
    f32x4 kk = *(const f32x4*)(K4 + ((ch0 + k) << 2));
    float a = cb[ch0 + k] + (float)r0[k]*kk[0] + (float)r1[k]*kk[1]
            + (float)r2[k]*kk[2] + (float)r3[k]*kk[3];
    o8[k] = (bf16_t)(a / (1.f + __expf(-a)));
  }
  *(bf16x8*)(xc + bt * INNER_ + ch0) = o8;
}

// ---------------- chunk sums for the w-scan, x8 vectorized -----------------------
__global__ __launch_bounds__(256)
void chunksum_kernel(const bf16_t* dt, float* sums) {
  int bc = blockIdx.x * 4 + (threadIdx.x >> 6);
  int ch0 = (threadIdx.x & 63) << 3;
  const bf16_t* p = dt + (long)bc * CHUNK_ * INNER_ + ch0;
  float a[8] = {};
  for (int i = 0; i < CHUNK_; i++) {
    bf16x8 v = *(const bf16x8*)(p + (long)i * INNER_);
#pragma unroll
    for (int k = 0; k < 8; k++) a[k] += (float)v[k];
  }
  float* o = sums + (long)bc * INNER_ + ch0;
#pragma unroll
  for (int k = 0; k < 8; k++) o[k] = a[k];
}

// y = xc * w * silu(z) in place over xc; chunk-prefix computed on the fly ----------
__global__ __launch_bounds__(256)
void y_kernel(const bf16_t* dt, const bf16_t* xz, bf16_t* xc, const float* sums) {
  int bc = blockIdx.x * 4 + (threadIdx.x >> 6);
  int b = bc >> 5;           // NCHUNK_ = 32
  int c = bc & 31;
  int ch0 = (threadIdx.x & 63) << 3;
  float acc[8] = {};
  const float* sp = sums + (long)b * NCHUNK_ * INNER_ + ch0;
  for (int cp = 0; cp < c; cp++) {
#pragma unroll
    for (int k = 0; k < 8; k++) acc[k] += sp[(long)cp * INNER_ + k];
  }
  long bt0 = (long)bc * CHUNK_;
  for (int i = 0; i < CHUNK_; i++) {
    long bt = bt0 + i;
    bf16x8 d8 = *(const bf16x8*)(dt + bt * INNER_ + ch0);
    bf16x8 z8 = *(const bf16x8*)(xz + bt * (2*INNER_) + INNER_ + ch0);
    bf16x8 x8 = *(const bf16x8*)(xc + bt * INNER_ + ch0);
    bf16x8 o8;
#pragma unroll
    for (int k = 0; k < 8; k++) {
      acc[k] += (float)d8[k];
      float w = __expf(-0.1f * acc[k]);
      float zz = (float)z8[k];
      float sz = zz / (1.f + __expf(-zz));
      o8[k] = (bf16_t)((float)x8[k] * w * sz);
    }
    *(bf16x8*)(xc + bt * INNER_ + ch0) = o8;
  }
}

// ---------------- log_softmax over 41 (one wave per row) -------------------------
__global__ __launch_bounds__(256)
void lsm_kernel(const float* logits, float* out) {
  int row = (blockIdx.x << 2) + (threadIdx.x >> 6);
  int lane = threadIdx.x & 63;
  float v = (lane < 41) ? logits[(long)row * 41 + lane] : -3.4e38f;
  float m = v;
#pragma unroll
  for (int off = 1; off < 64; off <<= 1) m = fmaxf(m, __shfl_xor(m, off));
  float e = (lane < 41) ? expf(v - m) : 0.f;
  float ssum = e;
#pragma unroll
  for (int off = 1; off < 64; off <<= 1) ssum += __shfl_xor(ssum, off);
  float ls = logf(ssum);
  if (lane < 41) out[(long)row * 41 + lane] = v - m - ls;
}

// ---------------- fp32 (R,C) -> bf16 (C,R) transpose, batched via z --------------
__global__ void tconv_kernel(const float* in, bf16_t* out, int R, int C) {
  __shared__ float tile[32][33];
  const float* ip = in + (long)blockIdx.z * R * C;
  bf16_t* op = out + (long)blockIdx.z * R * C;
  int c0 = blockIdx.x << 5, r0 = blockIdx.y << 5;
  int tx = threadIdx.x, ty = threadIdx.y;
  for (int i = ty; i < 32; i += 8) {
    int r = r0 + i, c = c0 + tx;
    tile[i][tx] = (r < R && c < C) ? ip[(long)r * C + c] : 0.f;
  }
  __syncthreads();
  for (int i = ty; i < 32; i += 8) {
    int c = c0 + i, r = r0 + tx;
    if (c < C && r < R) op[(long)c * R + r] = (bf16_t)tile[tx][i];
  }
}

__global__ void cvt_kernel(const float* in, bf16_t* out, long n) {
  long i = ((long)blockIdx.x * blockDim.x + threadIdx.x) << 3;
  if (i >= n) return;
  f32x4 a = *(const f32x4*)(in + i);
  f32x4 b = *(const f32x4*)(in + i + 4);
  bf16x8 o;
#pragma unroll
  for (int k = 0; k < 4; k++) { o[k] = (bf16_t)a[k]; o[k+4] = (bf16_t)b[k]; }
  *(bf16x8*)(out + i) = o;
}

__global__ void zfill_kernel(bf16_t* p, int n) {
  int i = blockIdx.x * 256 + threadIdx.x;
  if (i < n) p[i] = (bf16_t)0.f;
}

extern "C" void kernel_launch(void* const* d_in, const int* in_sizes, int n_in,
                              void* d_out, int out_size, void* d_ws, size_t ws_size,
                              hipStream_t stream) {
  (void)in_sizes; (void)n_in; (void)out_size;
  const float* x         = (const float*)d_in[0];
  const int*   day_ids   = (const int*)d_in[1];
  const float* adapter_W = (const float*)d_in[2];
  const float* adapter_b = (const float*)d_in[3];
  const float* cW1       = (const float*)d_in[4];
  const float* cb1       = (const float*)d_in[5];
  const float* cln1_s    = (const float*)d_in[6];
  const float* cln1_b    = (const float*)d_in[7];
  const float* cW2       = (const float*)d_in[8];
  const float* cb2       = (const float*)d_in[9];
  const float* cln2_s    = (const float*)d_in[10];
  const float* cln2_b    = (const float*)d_in[11];
  const float* m_in      = (const float*)d_in[12];
  const float* m_convK   = (const float*)d_in[13];
  const float* m_convB   = (const float*)d_in[14];
  const float* m_dtW     = (const float*)d_in[15];
  const float* m_dtB     = (const float*)d_in[16];
  const float* m_out     = (const float*)d_in[17];
  const float* proj_W    = (const float*)d_in[18];
  const float* proj_b    = (const float*)d_in[19];
  const float* norm_s    = (const float*)d_in[20];
  const float* norm_b    = (const float*)d_in[21];
  const float* outW      = (const float*)d_in[22];
  const float* outb      = (const float*)d_in[23];
  float* out = (float*)d_out;

  char* ws = (char*)d_ws;
  size_t off = 0;
  auto alloc = [&](size_t bytes) -> char* {
    char* p = ws + off;
    off += (bytes + 255) & ~(size_t)255;
    return p;
  };
  // ---- fixed: transposed bf16 weights (~33 MB) ----
  bf16_t* adapterT = (bf16_t*)alloc((size_t)45*512*512*2);
  bf16_t* cW1T     = (bf16_t*)alloc((size_t)256*512*2);
  bf16_t* cW2T     = (bf16_t*)alloc((size_t)256*256*2);
  bf16_t* m_inT    = (bf16_t*)alloc((size_t)6*1024*256*2);
  bf16_t* m_dtWT   = (bf16_t*)alloc((size_t)6*512*512*2);
  bf16_t* m_outT   = (bf16_t*)alloc((size_t)6*256*512*2);
  bf16_t* projT    = (bf16_t*)alloc((size_t)3*256*512*2);
  bf16_t* outWT    = (bf16_t*)alloc((size_t)128*256*2);

  // ---- adaptive group size: largest Bg whose regions fit ws_size ----
  int Bg = 0;
  {
    const int cands[6] = {32, 16, 8, 4, 2, 1};
    for (int ci = 0; ci < 6; ci++) {
      int c = cands[ci];
      size_t Mg = (size_t)c * T_;
      size_t need = Mg*2048 + 3*(Mg*1024) + Mg*512 + (size_t)c*NCHUNK_*INNER_*4
                    + 8*256;  // alignment slack
      if (off + need <= ws_size) { Bg = c; break; }
    }
  }
  if (Bg == 0) return;  // workspace too small to run at all
  const size_t Mg = (size_t)Bg * T_;
  char*  xzR  = alloc(Mg * 2048);          // xz (Mg x 1024 bf16); also x_bf, logits
  char*  xcR  = alloc(Mg * 1024);          // xc / y (Mg x 512 bf16); also h0
  char*  dtR  = alloc(Mg * 1024);          // dt (Mg x 512 bf16); also tmpF (Mg x 256 f32)
  char*  swR  = alloc(Mg * 1024);          // swcat (Mg x 512 bf16); also h1
  bf16_t* hG  = (bf16_t*)alloc(Mg * 512);  // h (Mg x 256 bf16)
  float* sums = (float*)alloc((size_t)Bg * NCHUNK_ * INNER_ * 4);

  // ---- weight conversion/transpose (once) ----
  zfill_kernel<<<128, 256, 0, stream>>>(outWT, 128*256);
  dim3 tb(32, 8);
  tconv_kernel<<<dim3(16,16,45), tb, 0, stream>>>(adapter_W, adapterT, 512, 512);
  tconv_kernel<<<dim3(8,16,1),  tb, 0, stream>>>(cW1,  cW1T,  512, 256);
  tconv_kernel<<<dim3(8,8,1),   tb, 0, stream>>>(cW2,  cW2T,  256, 256);
  tconv_kernel<<<dim3(32,8,6),  tb, 0, stream>>>(m_in, m_inT, 256, 1024);
  tconv_kernel<<<dim3(16,16,6), tb, 0, stream>>>(m_dtW, m_dtWT, 512, 512);
  tconv_kernel<<<dim3(8,16,6),  tb, 0, stream>>>(m_out, m_outT, 512, 256);
  tconv_kernel<<<dim3(8,16,3),  tb, 0, stream>>>(proj_W, projT, 512, 256);
  tconv_kernel<<<dim3(2,8,1),   tb, 0, stream>>>(outW, outWT, 256, 41);

  auto gemm = [&](const bf16_t* A, const bf16_t* Bt, const float* bias,
                  float* outF, bf16_t* outB, int K, int N, int ldout, int colOff,
                  int act, int revA, int revC, const int* days, long bsBt, int bsBias,
                  int nValid) {
    GemmP p;
    p.A = A; p.Bt = Bt; p.bias = bias; p.outF = outF; p.outB = outB;
    p.day_ids = days; p.bStrideBt = bsBt; p.bStrideBias = bsBias;
    p.K = K; p.N = N; p.ldout = ldout; p.colOff = colOff;
    p.act = act; p.revA = revA; p.revC = revC; p.nValid = nValid;
    gemm_kernel<<<dim3((unsigned)(Mg/128), N/128), 256, 0, stream>>>(p);
  };

  for (int b0 = 0; b0 < B_; b0 += Bg) {
    const float* xg = x + (size_t)b0 * T_ * 512;

    // ---- x -> bf16 ----
    bf16_t* x_bf = (bf16_t*)xzR;
    cvt_kernel<<<(unsigned)(Mg/4), 256, 0, stream>>>(xg, x_bf, (long)Mg*512);

    // ---- adapter: h0 = softsign(x @ W[day] + b[day]) ----
    bf16_t* h0 = (bf16_t*)xcR;
    gemm(x_bf, adapterT, adapter_b, nullptr, h0, 512, 512, 512, 0, /*act*/1, 0, 0,
         day_ids + b0, (long)512*512, 512, 512);

    // ---- h1 = silu(LN(h0 @ cW1 + cb1)) ----
    float* tmpF = (float*)dtR;
    gemm(h0, cW1T, cb1, tmpF, nullptr, 512, 256, 256, 0, 0, 0, 0, nullptr, 0, 0, 256);
    bf16_t* h1 = (bf16_t*)swR;
    ln_kernel<<<(unsigned)(Mg/4), 256, 0, stream>>>(tmpF, nullptr, cln1_s, cln1_b, h1, 1);

    // ---- h = silu(LN(h1 @ cW2 + cb2)) ----
    gemm(h1, cW2T, cb2, tmpF, nullptr, 256, 256, 256, 0, 0, 0, 0, nullptr, 0, 0, 256);
    ln_kernel<<<(unsigned)(Mg/4), 256, 0, stream>>>(tmpF, nullptr, cln2_s, cln2_b, hG, 1);

    bf16_t* xz    = (bf16_t*)xzR;
    bf16_t* xc    = (bf16_t*)xcR;
    bf16_t* dt    = (bf16_t*)dtR;
    bf16_t* swcat = (bf16_t*)swR;

    for (int l = 0; l < L_; l++) {
      for (int dir = 0; dir < 2; dir++) {
        int ld = l*2 + dir;
        // xz = h @ Win (reversed read of h for dir=1)
        gemm(hG, m_inT + (size_t)ld*1024*256, nullptr, nullptr, xz,
             256, 1024, 1024, 0, 0, /*revA*/dir, 0, nullptr, 0, 0, 1024);
        // xc = silu(dwconv(xi) + convB)
        conv_kernel<<<(unsigned)(Mg/4), 256, 0, stream>>>(
            xz, m_convK + (size_t)ld*512*4, m_convB + (size_t)ld*512, xc);
        // dt = softplus(xc @ dtW + dtB)
        gemm(xc, m_dtWT + (size_t)ld*512*512, m_dtB + (size_t)ld*512, nullptr, dt,
             512, 512, 512, 0, /*act*/2, 0, 0, nullptr, 0, 0, 512);
        // w = exp(-0.1*cumsum(dt)); y = xc * w * silu(z)   (in place over xc)
        chunksum_kernel<<<(unsigned)(Bg*8), 256, 0, stream>>>(dt, sums);
        y_kernel<<<(unsigned)(Bg*8), 256, 0, stream>>>(dt, xz, xc, sums);
        // swcat[:, dir*256:...] = y @ Wout (store reversed for dir=1)
        gemm(xc, m_outT + (size_t)ld*256*512, nullptr, nullptr, swcat,
             512, 256, 512, dir*256, 0, 0, /*revC*/dir, nullptr, 0, 0, 256);
      }
      // combined = swcat @ proj_W + proj_b; h = LN(h + combined)
      float* tmpF2 = (float*)dtR;
      gemm(swcat, projT + (size_t)l*256*512, proj_b + (size_t)l*256, tmpF2, nullptr,
           512, 256, 256, 0, 0, 0, 0, nullptr, 0, 0, 256);
      ln_kernel<<<(unsigned)(Mg/4), 256, 0, stream>>>(tmpF2, hG, norm_s + (size_t)l*256,
                                                      norm_b + (size_t)l*256, hG, 0);
    }

    // ---- logits + log_softmax ----
    float* logits = (float*)xzR;
    gemm(hG, outWT, outb, logits, nullptr, 256, 128, 41, 0, 0, 0, 0,
         nullptr, 0, 0, 41);
    lsm_kernel<<<(unsigned)(Mg/4), 256, 0, stream>>>(logits, out + (size_t)b0 * T_ * 41);
  }
}

// Round 4
// 2878.970 us; speedup vs baseline: 1.2163x; 1.1460x over previous
//
#include <hip/hip_runtime.h>
#include <hip/hip_bf16.h>
#include <cstdint>
#include <math.h>

typedef __bf16 bf16_t;
typedef bf16_t bf16x8 __attribute__((ext_vector_type(8)));
typedef float f32x4 __attribute__((ext_vector_type(4)));

#define B_ 32
#define T_ 2048
#define D_ 256
#define INNER_ 512
#define L_ 3
#define CHUNK_ 64
#define NCHUNK_ (T_/CHUNK_) // 32

typedef const __attribute__((address_space(1))) void* gas_t;
typedef __attribute__((address_space(3))) void* las_t;
__device__ __forceinline__ void gll16(const void* g, void* l) {
  __builtin_amdgcn_global_load_lds((gas_t)g, (las_t)l, 16, 0, 0);
}

struct GemmP {
  const bf16_t* A;
  const bf16_t* Bt;
  const float* bias;
  float* outF;
  bf16_t* outB;
  const int* day_ids;   // already offset by group base batch
  long bStrideBt;
  int bStrideBias;
  int K, N, ldout, colOff, act, revA, revC, nValid;
};

// ---------------- GEMM: C = A(MxK) * Bt(NxK)^T, bf16 in, fp32 acc ----------------
// Double-buffered LDS (prefetch tile k+1 via global_load_lds before computing k;
// single barrier per iteration). Swizzle: global 16B chunk (r,c) -> byte
// r*64 + (((c + (r>>2))&3)<<4), applied on the global source side (DMA dest is
// fixed tid*16); fragment reads then alias each bank exactly 2-way (free).
__global__ __launch_bounds__(256, 4)
void gemm_kernel(GemmP p) {
  __shared__ bf16_t As[2*128*32];   // 16 KB
  __shared__ bf16_t Bs[2*128*32];   // 16 KB
  const int tid = threadIdx.x;
  const int wave = tid >> 6, lane = tid & 63;
  const int m0 = blockIdx.x << 7, n0 = blockIdx.y << 7;
  const bf16_t* Bt = p.Bt;
  const float* bias = p.bias;
  if (p.day_ids) {
    int day = p.day_ids[m0 >> 11];      // 2048 rows per batch
    Bt += (long)day * p.bStrideBt;
    if (bias) bias += (long)day * p.bStrideBias;
  }
  const int K = p.K;
  const int srow = tid >> 2;                      // 0..63
  const int sc = ((tid & 3) - (tid >> 4)) & 3;    // global chunk this lane stages
  const int sk = sc << 3;                         // element offset of that chunk

  int ar0 = m0 + srow, ar1 = m0 + srow + 64;
  if (p.revA) {
    int t0 = ar0 & (T_-1); ar0 = ar0 - t0 + (T_-1 - t0);
    int t1 = ar1 & (T_-1); ar1 = ar1 - t1 + (T_-1 - t1);
  }
  const bf16_t* aP0 = p.A + (long)ar0 * K + sk;
  const bf16_t* aP1 = p.A + (long)ar1 * K + sk;
  const bf16_t* bP0 = Bt + (long)(n0 + srow) * K + sk;
  const bf16_t* bP1 = bP0 + (long)64 * K;

  char* aL = (char*)As + wave * 1024;   // +4096: rows 64-127; +8192: buffer 1
  char* bL = (char*)Bs + wave * 1024;

  f32x4 acc[4][4] = {};
  const int mw = ((wave >> 1) << 6), nw = ((wave & 1) << 6);
  const int fr = lane & 15;
  const int foff = (((lane >> 4) + (fr >> 2)) & 3) << 4;  // swizzled chunk byte off

  // prologue: stage tile 0 into buffer 0
  gll16(aP0, aL);
  gll16(aP1, aL + 4096);
  gll16(bP0, bL);
  gll16(bP1, bL + 4096);
  __syncthreads();

  const int nIter = K >> 5;
  for (int it = 0; it < nIter; ++it) {
    const int cur = (it & 1) << 13;     // byte offset of current buffer
    const int nxt = cur ^ 8192;
    if (it + 1 < nIter) {               // prefetch next tile into other buffer
      const int k1 = (it + 1) << 5;
      gll16(aP0 + k1, aL + nxt);
      gll16(aP1 + k1, aL + nxt + 4096);
      gll16(bP0 + k1, bL + nxt);
      gll16(bP1 + k1, bL + nxt + 4096);
    }
    bf16x8 af[4], bfr[4];
#pragma unroll
    for (int i = 0; i < 4; i++)
      af[i] = *(const bf16x8*)((char*)As + cur + (mw + i*16 + fr)*64 + foff);
#pragma unroll
    for (int j = 0; j < 4; j++)
      bfr[j] = *(const bf16x8*)((char*)Bs + cur + (nw + j*16 + fr)*64 + foff);
#pragma unroll
    for (int i = 0; i < 4; i++)
#pragma unroll
      for (int j = 0; j < 4; j++)
        acc[i][j] = __builtin_amdgcn_mfma_f32_16x16x32_bf16(af[i], bfr[j], acc[i][j], 0, 0, 0);
    __syncthreads();   // drains prefetch vmcnt AFTER compute; guards cur reuse
  }

  const int cn = lane & 15, rq = (lane >> 4) << 2;
#pragma unroll
  for (int i = 0; i < 4; i++) {
#pragma unroll
    for (int r = 0; r < 4; r++) {
      int gr = m0 + mw + i*16 + rq + r;
      int orow = gr;
      if (p.revC) { int t = gr & (T_-1); orow = gr - t + (T_-1 - t); }
      long rowOff = (long)orow * p.ldout + p.colOff;
#pragma unroll
      for (int j = 0; j < 4; j++) {
        int col = n0 + nw + j*16 + cn;
        if (col >= p.nValid) continue;
        float v = acc[i][j][r];
        if (bias) v += bias[col];
        if (p.act == 1) {
          v = v / (1.f + fabsf(v));                                   // softsign
        } else if (p.act == 2) {                                      // softplus
          float e = __expf(-fabsf(v));
          v = fmaxf(v, 0.f) + __logf(1.f + e);
        }
        if (p.outF) p.outF[rowOff + col] = v;
        if (p.outB) p.outB[rowOff + col] = (bf16_t)v;
      }
    }
  }
}

// ---------------- LayerNorm (one wave per 256-wide row) --------------------------
__global__ __launch_bounds__(256)
void ln_kernel(const float* in, const bf16_t* resid, const float* s, const float* bb,
               bf16_t* outB, int doSilu) {
  int row = (blockIdx.x << 2) + (threadIdx.x >> 6);
  int lane = threadIdx.x & 63;
  long base = (long)row * D_ + (lane << 2);
  f32x4 v = *(const f32x4*)(in + base);
  if (resid) {
#pragma unroll
    for (int k = 0; k < 4; k++) v[k] += (float)resid[base + k];
  }
  float s1 = v[0] + v[1] + v[2] + v[3];
  float s2 = v[0]*v[0] + v[1]*v[1] + v[2]*v[2] + v[3]*v[3];
#pragma unroll
  for (int off = 1; off < 64; off <<= 1) {
    s1 += __shfl_xor(s1, off);
    s2 += __shfl_xor(s2, off);
  }
  float mean = s1 * (1.f / D_);
  float var = s2 * (1.f / D_) - mean * mean;
  float inv = rsqrtf(var + 1e-5f);
  f32x4 sv = *(const f32x4*)(s + (lane << 2));
  f32x4 bv = *(const f32x4*)(bb + (lane << 2));
#pragma unroll
  for (int k = 0; k < 4; k++) {
    float val = (v[k] - mean) * inv * sv[k] + bv[k];
    if (doSilu) val = val / (1.f + __expf(-val));
    outB[base + k] = (bf16_t)val;
  }
}

// ---------------- depthwise conv (taps t-2..t+1) + bias + silu, x8 vectorized ----
__global__ __launch_bounds__(256)
void conv_kernel(const bf16_t* xz, const float* K4, const float* cb, bf16_t* xc) {
  long idx = (long)blockIdx.x * 256 + threadIdx.x;
  int ch0 = ((int)(idx & 63)) << 3;
  long bt = idx >> 6;
  int t = (int)(bt & (T_-1));
  const bf16_t* base = xz + bt * (2*INNER_) + ch0;
  bf16x8 r0, r1, r2, r3;
  r2 = *(const bf16x8*)(base);
#pragma unroll
  for (int k = 0; k < 8; k++) { r0[k] = (bf16_t)0.f; r1[k] = (bf16_t)0.f; r3[k] = (bf16_t)0.f; }
  if (t >= 2) r0 = *(const bf16x8*)(base - 2*(2*INNER_));
  if (t >= 1) r1 = *(const bf16x8*)(base - (2*INNER_));
  if (t < T_-1) r3 = *(const bf16x8*)(base + (2*INNER_));
  bf16x8 o8;
#pragma unroll
  for (int k = 0; k < 8; k++) {
    f32x4 kk = *(const f32x4*)(K4 + ((ch0 + k) << 2));
    float a = cb[ch0 + k] + (float)r0[k]*kk[0] + (float)r1[k]*kk[1]
            + (float)r2[k]*kk[2] + (float)r3[k]*kk[3];
    o8[k] = (bf16_t)(a / (1.f + __expf(-a)));
  }
  *(bf16x8*)(xc + bt * INNER_ + ch0) = o8;
}

// ---------------- chunk sums for the w-scan, x8 vectorized -----------------------
__global__ __launch_bounds__(256)
void chunksum_kernel(const bf16_t* dt, float* sums) {
  int bc = blockIdx.x * 4 + (threadIdx.x >> 6);
  int ch0 = (threadIdx.x & 63) << 3;
  const bf16_t* p = dt + (long)bc * CHUNK_ * INNER_ + ch0;
  float a[8] = {};
  for (int i = 0; i < CHUNK_; i++) {
    bf16x8 v = *(const bf16x8*)(p + (long)i * INNER_);
#pragma unroll
    for (int k = 0; k < 8; k++) a[k] += (float)v[k];
  }
  float* o = sums + (long)bc * INNER_ + ch0;
#pragma unroll
  for (int k = 0; k < 8; k++) o[k] = a[k];
}

// y = xc * w * silu(z) in place over xc; chunk-prefix computed on the fly ----------
__global__ __launch_bounds__(256)
void y_kernel(const bf16_t* dt, const bf16_t* xz, bf16_t* xc, const float* sums) {
  int bc = blockIdx.x * 4 + (threadIdx.x >> 6);
  int b = bc >> 5;           // NCHUNK_ = 32
  int c = bc & 31;
  int ch0 = (threadIdx.x & 63) << 3;
  float acc[8] = {};
  const float* sp = sums + (long)b * NCHUNK_ * INNER_ + ch0;
  for (int cp = 0; cp < c; cp++) {
#pragma unroll
    for (int k = 0; k < 8; k++) acc[k] += sp[(long)cp * INNER_ + k];
  }
  long bt0 = (long)bc * CHUNK_;
  for (int i = 0; i < CHUNK_; i++) {
    long bt = bt0 + i;
    bf16x8 d8 = *(const bf16x8*)(dt + bt * INNER_ + ch0);
    bf16x8 z8 = *(const bf16x8*)(xz + bt * (2*INNER_) + INNER_ + ch0);
    bf16x8 x8 = *(const bf16x8*)(xc + bt * INNER_ + ch0);
    bf16x8 o8;
#pragma unroll
    for (int k = 0; k < 8; k++) {
      acc[k] += (float)d8[k];
      float w = __expf(-0.1f * acc[k]);
      float zz = (float)z8[k];
      float sz = zz / (1.f + __expf(-zz));
      o8[k] = (bf16_t)((float)x8[k] * w * sz);
    }
    *(bf16x8*)(xc + bt * INNER_ + ch0) = o8;
  }
}

// ---------------- log_softmax over 41 (one wave per row) -------------------------
__global__ __launch_bounds__(256)
void lsm_kernel(const float* logits, float* out) {
  int row = (blockIdx.x << 2) + (threadIdx.x >> 6);
  int lane = threadIdx.x & 63;
  float v = (lane < 41) ? logits[(long)row * 41 + lane] : -3.4e38f;
  float m = v;
#pragma unroll
  for (int off = 1; off < 64; off <<= 1) m = fmaxf(m, __shfl_xor(m, off));
  float e = (lane < 41) ? __expf(v - m) : 0.f;
  float ssum = e;
#pragma unroll
  for (int off = 1; off < 64; off <<= 1) ssum += __shfl_xor(ssum, off);
  float ls = __logf(ssum);
  if (lane < 41) out[(long)row * 41 + lane] = v - m - ls;
}

// ---------------- fp32 (R,C) -> bf16 (C,R) transpose, batched via z --------------
__global__ void tconv_kernel(const float* in, bf16_t* out, int R, int C) {
  __shared__ float tile[32][33];
  const float* ip = in + (long)blockIdx.z * R * C;
  bf16_t* op = out + (long)blockIdx.z * R * C;
  int c0 = blockIdx.x << 5, r0 = blockIdx.y << 5;
  int tx = threadIdx.x, ty = threadIdx.y;
  for (int i = ty; i < 32; i += 8) {
    int r = r0 + i, c = c0 + tx;
    tile[i][tx] = (r < R && c < C) ? ip[(long)r * C + c] : 0.f;
  }
  __syncthreads();
  for (int i = ty; i < 32; i += 8) {
    int c = c0 + i, r = r0 + tx;
    if (c < C && r < R) op[(long)c * R + r] = (bf16_t)tile[tx][i];
  }
}

__global__ void cvt_kernel(const float* in, bf16_t* out, long n) {
  long i = ((long)blockIdx.x * blockDim.x + threadIdx.x) << 3;
  if (i >= n) return;
  f32x4 a = *(const f32x4*)(in + i);
  f32x4 b = *(const f32x4*)(in + i + 4);
  bf16x8 o;
#pragma unroll
  for (int k = 0; k < 4; k++) { o[k] = (bf16_t)a[k]; o[k+4] = (bf16_t)b[k]; }
  *(bf16x8*)(out + i) = o;
}

__global__ void zfill_kernel(bf16_t* p, int n) {
  int i = blockIdx.x * 256 + threadIdx.x;
  if (i < n) p[i] = (bf16_t)0.f;
}

extern "C" void kernel_launch(void* const* d_in, const int* in_sizes, int n_in,
                              void* d_out, int out_size, void* d_ws, size_t ws_size,
                              hipStream_t stream) {
  (void)in_sizes; (void)n_in; (void)out_size;
  const float* x         = (const float*)d_in[0];
  const int*   day_ids   = (const int*)d_in[1];
  const float* adapter_W = (const float*)d_in[2];
  const float* adapter_b = (const float*)d_in[3];
  const float* cW1       = (const float*)d_in[4];
  const float* cb1       = (const float*)d_in[5];
  const float* cln1_s    = (const float*)d_in[6];
  const float* cln1_b    = (const float*)d_in[7];
  const float* cW2       = (const float*)d_in[8];
  const float* cb2       = (const float*)d_in[9];
  const float* cln2_s    = (const float*)d_in[10];
  const float* cln2_b    = (const float*)d_in[11];
  const float* m_in      = (const float*)d_in[12];
  const float* m_convK   = (const float*)d_in[13];
  const float* m_convB   = (const float*)d_in[14];
  const float* m_dtW     = (const float*)d_in[15];
  const float* m_dtB     = (const float*)d_in[16];
  const float* m_out     = (const float*)d_in[17];
  const float* proj_W    = (const float*)d_in[18];
  const float* proj_b    = (const float*)d_in[19];
  const float* norm_s    = (const float*)d_in[20];
  const float* norm_b    = (const float*)d_in[21];
  const float* outW      = (const float*)d_in[22];
  const float* outb      = (const float*)d_in[23];
  float* out = (float*)d_out;

  char* ws = (char*)d_ws;
  size_t off = 0;
  auto alloc = [&](size_t bytes) -> char* {
    char* p = ws + off;
    off += (bytes + 255) & ~(size_t)255;
    return p;
  };
  // ---- fixed: transposed bf16 weights (~33 MB) ----
  bf16_t* adapterT = (bf16_t*)alloc((size_t)45*512*512*2);
  bf16_t* cW1T     = (bf16_t*)alloc((size_t)256*512*2);
  bf16_t* cW2T     = (bf16_t*)alloc((size_t)256*256*2);
  bf16_t* m_inT    = (bf16_t*)alloc((size_t)6*1024*256*2);
  bf16_t* m_dtWT   = (bf16_t*)alloc((size_t)6*512*512*2);
  bf16_t* m_outT   = (bf16_t*)alloc((size_t)6*256*512*2);
  bf16_t* projT    = (bf16_t*)alloc((size_t)3*256*512*2);
  bf16_t* outWT    = (bf16_t*)alloc((size_t)128*256*2);

  // ---- adaptive group size: largest Bg whose regions fit ws_size ----
  int Bg = 0;
  {
    const int cands[6] = {32, 16, 8, 4, 2, 1};
    for (int ci = 0; ci < 6; ci++) {
      int c = cands[ci];
      size_t Mg = (size_t)c * T_;
      size_t need = Mg*2048 + 3*(Mg*1024) + Mg*512 + (size_t)c*NCHUNK_*INNER_*4
                    + 8*256;  // alignment slack
      if (off + need <= ws_size) { Bg = c; break; }
    }
  }
  if (Bg == 0) return;  // workspace too small to run at all
  const size_t Mg = (size_t)Bg * T_;
  char*  xzR  = alloc(Mg * 2048);          // xz (Mg x 1024 bf16); also x_bf, logits
  char*  xcR  = alloc(Mg * 1024);          // xc / y (Mg x 512 bf16); also h0
  char*  dtR  = alloc(Mg * 1024);          // dt (Mg x 512 bf16); also tmpF (Mg x 256 f32)
  char*  swR  = alloc(Mg * 1024);          // swcat (Mg x 512 bf16); also h1
  bf16_t* hG  = (bf16_t*)alloc(Mg * 512);  // h (Mg x 256 bf16)
  float* sums = (float*)alloc((size_t)Bg * NCHUNK_ * INNER_ * 4);

  // ---- weight conversion/transpose (once) ----
  zfill_kernel<<<128, 256, 0, stream>>>(outWT, 128*256);
  dim3 tb(32, 8);
  tconv_kernel<<<dim3(16,16,45), tb, 0, stream>>>(adapter_W, adapterT, 512, 512);
  tconv_kernel<<<dim3(8,16,1),  tb, 0, stream>>>(cW1,  cW1T,  512, 256);
  tconv_kernel<<<dim3(8,8,1),   tb, 0, stream>>>(cW2,  cW2T,  256, 256);
  tconv_kernel<<<dim3(32,8,6),  tb, 0, stream>>>(m_in, m_inT, 256, 1024);
  tconv_kernel<<<dim3(16,16,6), tb, 0, stream>>>(m_dtW, m_dtWT, 512, 512);
  tconv_kernel<<<dim3(8,16,6),  tb, 0, stream>>>(m_out, m_outT, 512, 256);
  tconv_kernel<<<dim3(8,16,3),  tb, 0, stream>>>(proj_W, projT, 512, 256);
  tconv_kernel<<<dim3(2,8,1),   tb, 0, stream>>>(outW, outWT, 256, 41);

  auto gemm = [&](const bf16_t* A, const bf16_t* Bt, const float* bias,
                  float* outF, bf16_t* outB, int K, int N, int ldout, int colOff,
                  int act, int revA, int revC, const int* days, long bsBt, int bsBias,
                  int nValid) {
    GemmP p;
    p.A = A; p.Bt = Bt; p.bias = bias; p.outF = outF; p.outB = outB;
    p.day_ids = days; p.bStrideBt = bsBt; p.bStrideBias = bsBias;
    p.K = K; p.N = N; p.ldout = ldout; p.colOff = colOff;
    p.act = act; p.revA = revA; p.revC = revC; p.nValid = nValid;
    gemm_kernel<<<dim3((unsigned)(Mg/128), N/128), 256, 0, stream>>>(p);
  };

  for (int b0 = 0; b0 < B_; b0 += Bg) {
    const float* xg = x + (size_t)b0 * T_ * 512;

    // ---- x -> bf16 ----
    bf16_t* x_bf = (bf16_t*)xzR;
    cvt_kernel<<<(unsigned)(Mg/4), 256, 0, stream>>>(xg, x_bf, (long)Mg*512);

    // ---- adapter: h0 = softsign(x @ W[day] + b[day]) ----
    bf16_t* h0 = (bf16_t*)xcR;
    gemm(x_bf, adapterT, adapter_b, nullptr, h0, 512, 512, 512, 0, /*act*/1, 0, 0,
         day_ids + b0, (long)512*512, 512, 512);

    // ---- h1 = silu(LN(h0 @ cW1 + cb1)) ----
    float* tmpF = (float*)dtR;
    gemm(h0, cW1T, cb1, tmpF, nullptr, 512, 256, 256, 0, 0, 0, 0, nullptr, 0, 0, 256);
    bf16_t* h1 = (bf16_t*)swR;
    ln_kernel<<<(unsigned)(Mg/4), 256, 0, stream>>>(tmpF, nullptr, cln1_s, cln1_b, h1, 1);

    // ---- h = silu(LN(h1 @ cW2 + cb2)) ----
    gemm(h1, cW2T, cb2, tmpF, nullptr, 256, 256, 256, 0, 0, 0, 0, nullptr, 0, 0, 256);
    ln_kernel<<<(unsigned)(Mg/4), 256, 0, stream>>>(tmpF, nullptr, cln2_s, cln2_b, hG, 1);

    bf16_t* xz    = (bf16_t*)xzR;
    bf16_t* xc    = (bf16_t*)xcR;
    bf16_t* dt    = (bf16_t*)dtR;
    bf16_t* swcat = (bf16_t*)swR;

    for (int l = 0; l < L_; l++) {
      for (int dir = 0; dir < 2; dir++) {
        int ld = l*2 + dir;
        // xz = h @ Win (reversed read of h for dir=1)
        gemm(hG, m_inT + (size_t)ld*1024*256, nullptr, nullptr, xz,
             256, 1024, 1024, 0, 0, /*revA*/dir, 0, nullptr, 0, 0, 1024);
        // xc = silu(dwconv(xi) + convB)
        conv_kernel<<<(unsigned)(Mg/4), 256, 0, stream>>>(
            xz, m_convK + (size_t)ld*512*4, m_convB + (size_t)ld*512, xc);
        // dt = softplus(xc @ dtW + dtB)
        gemm(xc, m_dtWT + (size_t)ld*512*512, m_dtB + (size_t)ld*512, nullptr, dt,
             512, 512, 512, 0, /*act*/2, 0, 0, nullptr, 0, 0, 512);
        // w = exp(-0.1*cumsum(dt)); y = xc * w * silu(z)   (in place over xc)
        chunksum_kernel<<<(unsigned)(Bg*8), 256, 0, stream>>>(dt, sums);
        y_kernel<<<(unsigned)(Bg*8), 256, 0, stream>>>(dt, xz, xc, sums);
        // swcat[:, dir*256:...] = y @ Wout (store reversed for dir=1)
        gemm(xc, m_outT + (size_t)ld*256*512, nullptr, nullptr, swcat,
             512, 256, 512, dir*256, 0, 0, /*revC*/dir, nullptr, 0, 0, 256);
      }
      // combined = swcat @ proj_W + proj_b; h = LN(h + combined)
      float* tmpF2 = (float*)dtR;
      gemm(swcat, projT + (size_t)l*256*512, proj_b + (size_t)l*256, tmpF2, nullptr,
           512, 256, 256, 0, 0, 0, 0, nullptr, 0, 0, 256);
      ln_kernel<<<(unsigned)(Mg/4), 256, 0, stream>>>(tmpF2, hG, norm_s + (size_t)l*256,
                                                      norm_b + (size_t)l*256, hG, 0);
    }

    // ---- logits + log_softmax ----
    float* logits = (float*)xzR;
    gemm(hG, outWT, outb, logits, nullptr, 256, 128, 41, 0, 0, 0, 0,
         nullptr, 0, 0, 41);
    lsm_kernel<<<(unsigned)(Mg/4), 256, 0, stream>>>(logits, out + (size_t)b0 * T_ * 41);
  }
}

// Round 5
// 2730.614 us; speedup vs baseline: 1.2824x; 1.0543x over previous
//
#include <hip/hip_runtime.h>
#include <hip/hip_bf16.h>
#include <cstdint>
#include <math.h>

typedef __bf16 bf16_t;
typedef bf16_t bf16x8 __attribute__((ext_vector_type(8)));
typedef bf16_t bf16x4 __attribute__((ext_vector_type(4)));
typedef float f32x4 __attribute__((ext_vector_type(4)));

#define B_ 32
#define T_ 2048
#define D_ 256
#define INNER_ 512
#define L_ 3
#define CHUNK_ 64
#define NCHUNK_ (T_/CHUNK_) // 32

typedef const __attribute__((address_space(1))) void* gas_t;
typedef __attribute__((address_space(3))) void* las_t;
__device__ __forceinline__ void gll16(const void* g, void* l) {
  __builtin_amdgcn_global_load_lds((gas_t)g, (las_t)l, 16, 0, 0);
}

struct GemmP {
  const bf16_t* A;
  const bf16_t* Bt;
  const float* bias;
  float* outF;
  bf16_t* outB;
  const int* day_ids;   // already offset by group base batch
  long bStrideBt;
  int bStrideBias;
  int K, N, ldout, colOff, act, revA, revC, nValid;
};

// ---------------- GEMM: C = A(MxK) * Bt(NxK)^T, bf16 in, fp32 acc ----------------
// 1-D grid + XCD-aware swizzle: bid%8 -> XCD (round-robin heuristic). XCD c owns a
// contiguous band of M-tiles; within the band, the N/128 column blocks of one
// M-tile are temporally adjacent on that XCD, so each 128-row A-tile is fetched
// from HBM once and re-served from the XCD-local L2.
// Double-buffered LDS staging via global_load_lds; swizzle chunk (r,c) -> byte
// r*64 + (((c + (r>>2))&3)<<4) applied on the global source side.
__global__ __launch_bounds__(256, 4)
void gemm_kernel(GemmP p) {
  __shared__ bf16_t As[2*128*32];   // 16 KB
  __shared__ bf16_t Bs[2*128*32];   // 16 KB
  const int tid = threadIdx.x;
  const int wave = tid >> 6, lane = tid & 63;

  // ---- swizzled block decode ----
  const int nb = p.N >> 7;                 // N-blocks (1,2,4,8)
  const int nbs = __builtin_ctz(nb);
  const int c8 = blockIdx.x & 7;           // XCD id under round-robin
  const int k8 = blockIdx.x >> 3;
  const int mGrp = (gridDim.x >> 3) >> nbs;  // M-tiles per XCD
  const int m0 = (c8 * mGrp + (k8 >> nbs)) << 7;
  const int n0 = (k8 & (nb - 1)) << 7;

  const bf16_t* Bt = p.Bt;
  const float* bias = p.bias;
  if (p.day_ids) {
    int day = p.day_ids[m0 >> 11];      // 2048 rows per batch
    Bt += (long)day * p.bStrideBt;
    if (bias) bias += (long)day * p.bStrideBias;
  }
  const int K = p.K;
  const int srow = tid >> 2;                      // 0..63
  const int sc = ((tid & 3) - (tid >> 4)) & 3;    // global chunk this lane stages
  const int sk = sc << 3;                         // element offset of that chunk

  int ar0 = m0 + srow, ar1 = m0 + srow + 64;
  if (p.revA) {
    int t0 = ar0 & (T_-1); ar0 = ar0 - t0 + (T_-1 - t0);
    int t1 = ar1 & (T_-1); ar1 = ar1 - t1 + (T_-1 - t1);
  }
  const bf16_t* aP0 = p.A + (long)ar0 * K + sk;
  const bf16_t* aP1 = p.A + (long)ar1 * K + sk;
  const bf16_t* bP0 = Bt + (long)(n0 + srow) * K + sk;
  const bf16_t* bP1 = bP0 + (long)64 * K;

  char* aL = (char*)As + wave * 1024;   // +4096: rows 64-127; +8192: buffer 1
  char* bL = (char*)Bs + wave * 1024;

  f32x4 acc[4][4] = {};
  const int mw = ((wave >> 1) << 6), nw = ((wave & 1) << 6);
  const int fr = lane & 15;
  const int foff = (((lane >> 4) + (fr >> 2)) & 3) << 4;  // swizzled chunk byte off

  // prologue: stage tile 0 into buffer 0
  gll16(aP0, aL);
  gll16(aP1, aL + 4096);
  gll16(bP0, bL);
  gll16(bP1, bL + 4096);
  __syncthreads();

  const int nIter = K >> 5;
  for (int it = 0; it < nIter; ++it) {
    const int cur = (it & 1) << 13;     // byte offset of current buffer
    const int nxt = cur ^ 8192;
    if (it + 1 < nIter) {               // prefetch next tile into other buffer
      const int k1 = (it + 1) << 5;
      gll16(aP0 + k1, aL + nxt);
      gll16(aP1 + k1, aL + nxt + 4096);
      gll16(bP0 + k1, bL + nxt);
      gll16(bP1 + k1, bL + nxt + 4096);
    }
    bf16x8 af[4], bfr[4];
#pragma unroll
    for (int i = 0; i < 4; i++)
      af[i] = *(const bf16x8*)((char*)As + cur + (mw + i*16 + fr)*64 + foff);
#pragma unroll
    for (int j = 0; j < 4; j++)
      bfr[j] = *(const bf16x8*)((char*)Bs + cur + (nw + j*16 + fr)*64 + foff);
#pragma unroll
    for (int i = 0; i < 4; i++)
#pragma unroll
      for (int j = 0; j < 4; j++)
        acc[i][j] = __builtin_amdgcn_mfma_f32_16x16x32_bf16(af[i], bfr[j], acc[i][j], 0, 0, 0);
    __syncthreads();   // drains prefetch vmcnt AFTER compute; guards cur reuse
  }

  const int cn = lane & 15, rq = (lane >> 4) << 2;
#pragma unroll
  for (int i = 0; i < 4; i++) {
#pragma unroll
    for (int r = 0; r < 4; r++) {
      int gr = m0 + mw + i*16 + rq + r;
      int orow = gr;
      if (p.revC) { int t = gr & (T_-1); orow = gr - t + (T_-1 - t); }
      long rowOff = (long)orow * p.ldout + p.colOff;
#pragma unroll
      for (int j = 0; j < 4; j++) {
        int col = n0 + nw + j*16 + cn;
        if (col >= p.nValid) continue;
        float v = acc[i][j][r];
        if (bias) v += bias[col];
        if (p.act == 1) {
          v = v / (1.f + fabsf(v));                                   // softsign
        } else if (p.act == 2) {                                      // softplus
          float e = __expf(-fabsf(v));
          v = fmaxf(v, 0.f) + __logf(1.f + e);
        }
        if (p.outF) p.outF[rowOff + col] = v;
        if (p.outB) p.outB[rowOff + col] = (bf16_t)v;
      }
    }
  }
}

// ---------------- LayerNorm (one wave per 256-wide row), bf16 in/out -------------
__global__ __launch_bounds__(256)
void ln_kernel(const bf16_t* in, const bf16_t* resid, const float* s, const float* bb,
               bf16_t* outB, int doSilu) {
  int row = (blockIdx.x << 2) + (threadIdx.x >> 6);
  int lane = threadIdx.x & 63;
  long base = (long)row * D_ + (lane << 2);
  bf16x4 iv = *(const bf16x4*)(in + base);
  float v[4];
#pragma unroll
  for (int k = 0; k < 4; k++) v[k] = (float)iv[k];
  if (resid) {
    bf16x4 rv = *(const bf16x4*)(resid + base);
#pragma unroll
    for (int k = 0; k < 4; k++) v[k] += (float)rv[k];
  }
  float s1 = v[0] + v[1] + v[2] + v[3];
  float s2 = v[0]*v[0] + v[1]*v[1] + v[2]*v[2] + v[3]*v[3];
#pragma unroll
  for (int off = 1; off < 64; off <<= 1) {
    s1 += __shfl_xor(s1, off);
    s2 += __shfl_xor(s2, off);
  }
  float mean = s1 * (1.f / D_);
  float var = s2 * (1.f / D_) - mean * mean;
  float inv = rsqrtf(var + 1e-5f);
  f32x4 sv = *(const f32x4*)(s + (lane << 2));
  f32x4 bv = *(const f32x4*)(bb + (lane << 2));
  bf16x4 ov;
#pragma unroll
  for (int k = 0; k < 4; k++) {
    float val = (v[k] - mean) * inv * sv[k] + bv[k];
    if (doSilu) val = val / (1.f + __expf(-val));
    ov[k] = (bf16_t)val;
  }
  *(bf16x4*)(outB + base) = ov;
}

// ---------------- depthwise conv (taps t-2..t+1) + bias + silu, x8 vectorized ----
__global__ __launch_bounds__(256)
void conv_kernel(const bf16_t* xz, const float* K4, const float* cb, bf16_t* xc) {
  long idx = (long)blockIdx.x * 256 + threadIdx.x;
  int ch0 = ((int)(idx & 63)) << 3;
  long bt = idx >> 6;
  int t = (int)(bt & (T_-1));
  const bf16_t* base = xz + bt * (2*INNER_) + ch0;
  bf16x8 r0, r1, r2, r3;
  r2 = *(const bf16x8*)(base);
#pragma unroll
  for (int k = 0; k < 8; k++) { r0[k] = (bf16_t)0.f; r1[k] = (bf16_t)0.f; r3[k] = (bf16_t)0.f; }
  if (t >= 2) r0 = *(const bf16x8*)(base - 2*(2*INNER_));
  if (t >= 1) r1 = *(const bf16x8*)(base - (2*INNER_));
  if (t < T_-1) r3 = *(const bf16x8*)(base + (2*INNER_));
  bf16x8 o8;
#pragma unroll
  for (int k = 0; k < 8; k++) {
    f32x4 kk = *(const f32x4*)(K4 + ((ch0 + k) << 2));
    float a = cb[ch0 + k] + (float)r0[k]*kk[0] + (float)r1[k]*kk[1]
            + (float)r2[k]*kk[2] + (float)r3[k]*kk[3];
    o8[k] = (bf16_t)(a / (1.f + __expf(-a)));
  }
  *(bf16x8*)(xc + bt * INNER_ + ch0) = o8;
}

// ---------------- chunk sums for the w-scan, x8 vectorized -----------------------
__global__ __launch_bounds__(256)
void chunksum_kernel(const bf16_t* dt, float* sums) {
  int bc = blockIdx.x * 4 + (threadIdx.x >> 6);
  int ch0 = (threadIdx.x & 63) << 3;
  const bf16_t* p = dt + (long)bc * CHUNK_ * INNER_ + ch0;
  float a[8] = {};
  for (int i = 0; i < CHUNK_; i++) {
    bf16x8 v = *(const bf16x8*)(p + (long)i * INNER_);
#pragma unroll
    for (int k = 0; k < 8; k++) a[k] += (float)v[k];
  }
  float* o = sums + (long)bc * INNER_ + ch0;
#pragma unroll
  for (int k = 0; k < 8; k++) o[k] = a[k];
}

// y = xc * w * silu(z) in place over xc; chunk-prefix computed on the fly ----------
__global__ __launch_bounds__(256)
void y_kernel(const bf16_t* dt, const bf16_t* xz, bf16_t* xc, const float* sums) {
  int bc = blockIdx.x * 4 + (threadIdx.x >> 6);
  int b = bc >> 5;           // NCHUNK_ = 32
  int c = bc & 31;
  int ch0 = (threadIdx.x & 63) << 3;
  float acc[8] = {};
  const float* sp = sums + (long)b * NCHUNK_ * INNER_ + ch0;
  for (int cp = 0; cp < c; cp++) {
#pragma unroll
    for (int k = 0; k < 8; k++) acc[k] += sp[(long)cp * INNER_ + k];
  }
  long bt0 = (long)bc * CHUNK_;
  for (int i = 0; i < CHUNK_; i++) {
    long bt = bt0 + i;
    bf16x8 d8 = *(const bf16x8*)(dt + bt * INNER_ + ch0);
    bf16x8 z8 = *(const bf16x8*)(xz + bt * (2*INNER_) + INNER_ + ch0);
    bf16x8 x8 = *(const bf16x8*)(xc + bt * INNER_ + ch0);
    bf16x8 o8;
#pragma unroll
    for (int k = 0; k < 8; k++) {
      acc[k] += (float)d8[k];
      float w = __expf(-0.1f * acc[k]);
      float zz = (float)z8[k];
      float sz = zz / (1.f + __expf(-zz));
      o8[k] = (bf16_t)((float)x8[k] * w * sz);
    }
    *(bf16x8*)(xc + bt * INNER_ + ch0) = o8;
  }
}

// ---------------- log_softmax over 41 (one wave per row) -------------------------
__global__ __launch_bounds__(256)
void lsm_kernel(const float* logits, float* out) {
  int row = (blockIdx.x << 2) + (threadIdx.x >> 6);
  int lane = threadIdx.x & 63;
  float v = (lane < 41) ? logits[(long)row * 41 + lane] : -3.4e38f;
  float m = v;
#pragma unroll
  for (int off = 1; off < 64; off <<= 1) m = fmaxf(m, __shfl_xor(m, off));
  float e = (lane < 41) ? __expf(v - m) : 0.f;
  float ssum = e;
#pragma unroll
  for (int off = 1; off < 64; off <<= 1) ssum += __shfl_xor(ssum, off);
  float ls = __logf(ssum);
  if (lane < 41) out[(long)row * 41 + lane] = v - m - ls;
}

// ---------------- fp32 (R,C) -> bf16 (C,R) transpose, batched via z --------------
__global__ void tconv_kernel(const float* in, bf16_t* out, int R, int C) {
  __shared__ float tile[32][33];
  const float* ip = in + (long)blockIdx.z * R * C;
  bf16_t* op = out + (long)blockIdx.z * R * C;
  int c0 = blockIdx.x << 5, r0 = blockIdx.y << 5;
  int tx = threadIdx.x, ty = threadIdx.y;
  for (int i = ty; i < 32; i += 8) {
    int r = r0 + i, c = c0 + tx;
    tile[i][tx] = (r < R && c < C) ? ip[(long)r * C + c] : 0.f;
  }
  __syncthreads();
  for (int i = ty; i < 32; i += 8) {
    int c = c0 + i, r = r0 + tx;
    if (c < C && r < R) op[(long)c * R + r] = (bf16_t)tile[tx][i];
  }
}

__global__ void cvt_kernel(const float* in, bf16_t* out, long n) {
  long i = ((long)blockIdx.x * blockDim.x + threadIdx.x) << 3;
  if (i >= n) return;
  f32x4 a = *(const f32x4*)(in + i);
  f32x4 b = *(const f32x4*)(in + i + 4);
  bf16x8 o;
#pragma unroll
  for (int k = 0; k < 4; k++) { o[k] = (bf16_t)a[k]; o[k+4] = (bf16_t)b[k]; }
  *(bf16x8*)(out + i) = o;
}

__global__ void zfill_kernel(bf16_t* p, int n) {
  int i = blockIdx.x * 256 + threadIdx.x;
  if (i < n) p[i] = (bf16_t)0.f;
}

extern "C" void kernel_launch(void* const* d_in, const int* in_sizes, int n_in,
                              void* d_out, int out_size, void* d_ws, size_t ws_size,
                              hipStream_t stream) {
  (void)in_sizes; (void)n_in; (void)out_size;
  const float* x         = (const float*)d_in[0];
  const int*   day_ids   = (const int*)d_in[1];
  const float* adapter_W = (const float*)d_in[2];
  const float* adapter_b = (const float*)d_in[3];
  const float* cW1       = (const float*)d_in[4];
  const float* cb1       = (const float*)d_in[5];
  const float* cln1_s    = (const float*)d_in[6];
  const float* cln1_b    = (const float*)d_in[7];
  const float* cW2       = (const float*)d_in[8];
  const float* cb2       = (const float*)d_in[9];
  const float* cln2_s    = (const float*)d_in[10];
  const float* cln2_b    = (const float*)d_in[11];
  const float* m_in      = (const float*)d_in[12];
  const float* m_convK   = (const float*)d_in[13];
  const float* m_convB   = (const float*)d_in[14];
  const float* m_dtW     = (const float*)d_in[15];
  const float* m_dtB     = (const float*)d_in[16];
  const float* m_out     = (const float*)d_in[17];
  const float* proj_W    = (const float*)d_in[18];
  const float* proj_b    = (const float*)d_in[19];
  const float* norm_s    = (const float*)d_in[20];
  const float* norm_b    = (const float*)d_in[21];
  const float* outW      = (const float*)d_in[22];
  const float* outb      = (const float*)d_in[23];
  float* out = (float*)d_out;

  char* ws = (char*)d_ws;
  size_t off = 0;
  auto alloc = [&](size_t bytes) -> char* {
    char* p = ws + off;
    off += (bytes + 255) & ~(size_t)255;
    return p;
  };
  // ---- fixed: transposed bf16 weights (~33 MB) ----
  bf16_t* adapterT = (bf16_t*)alloc((size_t)45*512*512*2);
  bf16_t* cW1T     = (bf16_t*)alloc((size_t)256*512*2);
  bf16_t* cW2T     = (bf16_t*)alloc((size_t)256*256*2);
  bf16_t* m_inT    = (bf16_t*)alloc((size_t)6*1024*256*2);
  bf16_t* m_dtWT   = (bf16_t*)alloc((size_t)6*512*512*2);
  bf16_t* m_outT   = (bf16_t*)alloc((size_t)6*256*512*2);
  bf16_t* projT    = (bf16_t*)alloc((size_t)3*256*512*2);
  bf16_t* outWT    = (bf16_t*)alloc((size_t)128*256*2);

  // ---- adaptive group size: largest Bg whose regions fit ws_size ----
  int Bg = 0;
  {
    const int cands[6] = {32, 16, 8, 4, 2, 1};
    for (int ci = 0; ci < 6; ci++) {
      int c = cands[ci];
      size_t Mg = (size_t)c * T_;
      size_t need = Mg*2048 + 3*(Mg*1024) + Mg*512 + (size_t)c*NCHUNK_*INNER_*4
                    + 8*256;  // alignment slack
      if (off + need <= ws_size) { Bg = c; break; }
    }
  }
  if (Bg == 0) return;  // workspace too small to run at all
  const size_t Mg = (size_t)Bg * T_;
  char*  xzR  = alloc(Mg * 2048);          // xz (Mg x 1024 bf16); also x_bf, logits
  char*  xcR  = alloc(Mg * 1024);          // xc / y (Mg x 512 bf16); also h0
  char*  dtR  = alloc(Mg * 1024);          // dt (Mg x 512 bf16); also tmp pre-LN bf16
  char*  swR  = alloc(Mg * 1024);          // swcat (Mg x 512 bf16); also h1
  bf16_t* hG  = (bf16_t*)alloc(Mg * 512);  // h (Mg x 256 bf16)
  float* sums = (float*)alloc((size_t)Bg * NCHUNK_ * INNER_ * 4);

  // ---- weight conversion/transpose (once) ----
  zfill_kernel<<<128, 256, 0, stream>>>(outWT, 128*256);
  dim3 tb(32, 8);
  tconv_kernel<<<dim3(16,16,45), tb, 0, stream>>>(adapter_W, adapterT, 512, 512);
  tconv_kernel<<<dim3(8,16,1),  tb, 0, stream>>>(cW1,  cW1T,  512, 256);
  tconv_kernel<<<dim3(8,8,1),   tb, 0, stream>>>(cW2,  cW2T,  256, 256);
  tconv_kernel<<<dim3(32,8,6),  tb, 0, stream>>>(m_in, m_inT, 256, 1024);
  tconv_kernel<<<dim3(16,16,6), tb, 0, stream>>>(m_dtW, m_dtWT, 512, 512);
  tconv_kernel<<<dim3(8,16,6),  tb, 0, stream>>>(m_out, m_outT, 512, 256);
  tconv_kernel<<<dim3(8,16,3),  tb, 0, stream>>>(proj_W, projT, 512, 256);
  tconv_kernel<<<dim3(2,8,1),   tb, 0, stream>>>(outW, outWT, 256, 41);

  auto gemm = [&](const bf16_t* A, const bf16_t* Bt, const float* bias,
                  float* outF, bf16_t* outB, int K, int N, int ldout, int colOff,
                  int act, int revA, int revC, const int* days, long bsBt, int bsBias,
                  int nValid) {
    GemmP p;
    p.A = A; p.Bt = Bt; p.bias = bias; p.outF = outF; p.outB = outB;
    p.day_ids = days; p.bStrideBt = bsBt; p.bStrideBias = bsBias;
    p.K = K; p.N = N; p.ldout = ldout; p.colOff = colOff;
    p.act = act; p.revA = revA; p.revC = revC; p.nValid = nValid;
    gemm_kernel<<<dim3((unsigned)((Mg/128) * (N/128))), 256, 0, stream>>>(p);
  };

  for (int b0 = 0; b0 < B_; b0 += Bg) {
    const float* xg = x + (size_t)b0 * T_ * 512;

    // ---- x -> bf16 ----
    bf16_t* x_bf = (bf16_t*)xzR;
    cvt_kernel<<<(unsigned)(Mg/4), 256, 0, stream>>>(xg, x_bf, (long)Mg*512);

    // ---- adapter: h0 = softsign(x @ W[day] + b[day]) ----
    bf16_t* h0 = (bf16_t*)xcR;
    gemm(x_bf, adapterT, adapter_b, nullptr, h0, 512, 512, 512, 0, /*act*/1, 0, 0,
         day_ids + b0, (long)512*512, 512, 512);

    // ---- h1 = silu(LN(h0 @ cW1 + cb1)) ----
    bf16_t* tmpB = (bf16_t*)dtR;
    gemm(h0, cW1T, cb1, nullptr, tmpB, 512, 256, 256, 0, 0, 0, 0, nullptr, 0, 0, 256);
    bf16_t* h1 = (bf16_t*)swR;
    ln_kernel<<<(unsigned)(Mg/4), 256, 0, stream>>>(tmpB, nullptr, cln1_s, cln1_b, h1, 1);

    // ---- h = silu(LN(h1 @ cW2 + cb2)) ----
    gemm(h1, cW2T, cb2, nullptr, tmpB, 256, 256, 256, 0, 0, 0, 0, nullptr, 0, 0, 256);
    ln_kernel<<<(unsigned)(Mg/4), 256, 0, stream>>>(tmpB, nullptr, cln2_s, cln2_b, hG, 1);

    bf16_t* xz    = (bf16_t*)xzR;
    bf16_t* xc    = (bf16_t*)xcR;
    bf16_t* dt    = (bf16_t*)dtR;
    bf16_t* swcat = (bf16_t*)swR;

    for (int l = 0; l < L_; l++) {
      for (int dir = 0; dir < 2; dir++) {
        int ld = l*2 + dir;
        // xz = h @ Win (reversed read of h for dir=1)
        gemm(hG, m_inT + (size_t)ld*1024*256, nullptr, nullptr, xz,
             256, 1024, 1024, 0, 0, /*revA*/dir, 0, nullptr, 0, 0, 1024);
        // xc = silu(dwconv(xi) + convB)
        conv_kernel<<<(unsigned)(Mg/4), 256, 0, stream>>>(
            xz, m_convK + (size_t)ld*512*4, m_convB + (size_t)ld*512, xc);
        // dt = softplus(xc @ dtW + dtB)
        gemm(xc, m_dtWT + (size_t)ld*512*512, m_dtB + (size_t)ld*512, nullptr, dt,
             512, 512, 512, 0, /*act*/2, 0, 0, nullptr, 0, 0, 512);
        // w = exp(-0.1*cumsum(dt)); y = xc * w * silu(z)   (in place over xc)
        chunksum_kernel<<<(unsigned)(Bg*8), 256, 0, stream>>>(dt, sums);
        y_kernel<<<(unsigned)(Bg*8), 256, 0, stream>>>(dt, xz, xc, sums);
        // swcat[:, dir*256:...] = y @ Wout (store reversed for dir=1)
        gemm(xc, m_outT + (size_t)ld*256*512, nullptr, nullptr, swcat,
             512, 256, 512, dir*256, 0, 0, /*revC*/dir, nullptr, 0, 0, 256);
      }
      // combined = swcat @ proj_W + proj_b; h = LN(h + combined)
      bf16_t* tmpB2 = (bf16_t*)dtR;
      gemm(swcat, projT + (size_t)l*256*512, proj_b + (size_t)l*256, nullptr, tmpB2,
           512, 256, 256, 0, 0, 0, 0, nullptr, 0, 0, 256);
      ln_kernel<<<(unsigned)(Mg/4), 256, 0, stream>>>(tmpB2, hG, norm_s + (size_t)l*256,
                                                      norm_b + (size_t)l*256, hG, 0);
    }

    // ---- logits + log_softmax ----
    float* logits = (float*)xzR;
    gemm(hG, outWT, outb, logits, nullptr, 256, 128, 41, 0, 0, 0, 0,
         nullptr, 0, 0, 41);
    lsm_kernel<<<(unsigned)(Mg/4), 256, 0, stream>>>(logits, out + (size_t)b0 * T_ * 41);
  }
}

// Round 6
// 2543.440 us; speedup vs baseline: 1.3768x; 1.0736x over previous
//
#include <hip/hip_runtime.h>
#include <hip/hip_bf16.h>
#include <cstdint>
#include <math.h>

typedef __bf16 bf16_t;
typedef bf16_t bf16x8 __attribute__((ext_vector_type(8)));
typedef bf16_t bf16x4 __attribute__((ext_vector_type(4)));
typedef float f32x4 __attribute__((ext_vector_type(4)));

#define B_ 32
#define T_ 2048
#define D_ 256
#define INNER_ 512
#define L_ 3
#define CHUNK_ 64
#define NCHUNK_ (T_/CHUNK_) // 32

typedef const __attribute__((address_space(1))) void* gas_t;
typedef __attribute__((address_space(3))) void* las_t;
__device__ __forceinline__ void gll16(const void* g, void* l) {
  __builtin_amdgcn_global_load_lds((gas_t)g, (las_t)l, 16, 0, 0);
}

struct GemmP {
  const bf16_t* A;
  const bf16_t* Bt;
  const float* bias;
  float* outF;
  bf16_t* outB;
  float* sums;          // act==3: per-chunk column sums of the activated output
  const int* day_ids;   // already offset by group base batch
  long bStrideBt;
  int bStrideBias;
  int K, N, ldout, colOff, act, revA, revC, nValid;
};

// ---------------- GEMM: C = A(MxK) * Bt(NxK)^T, bf16 in, fp32 acc ----------------
// XCD-aware 1-D grid swizzle (bid%8 -> XCD): each XCD's band re-serves A-tiles
// from its local L2 across the N-column blocks.
// Double-buffered LDS staging via global_load_lds; source-side chunk swizzle
// (r,c) -> byte r*64 + (((c + (r>>2))&3)<<4).
// MFMA operand order (b_frag, a_frag): puts n on D's reg axis -> each lane's
// f32x4 holds 4 CONSECUTIVE columns of one C row -> 8-B bf16x4 stores.
__global__ __launch_bounds__(256, 4)
void gemm_kernel(GemmP p) {
  __shared__ bf16_t As[2*128*32];   // 16 KB
  __shared__ bf16_t Bs[2*128*32];   // 16 KB
  const int tid = threadIdx.x;
  const int wave = tid >> 6, lane = tid & 63;

  // ---- swizzled block decode ----
  const int nb = p.N >> 7;                 // N-blocks (1,2,4,8)
  const int nbs = __builtin_ctz(nb);
  const int c8 = blockIdx.x & 7;           // XCD id under round-robin
  const int k8 = blockIdx.x >> 3;
  const int mGrp = (gridDim.x >> 3) >> nbs;  // M-tiles per XCD
  const int m0 = (c8 * mGrp + (k8 >> nbs)) << 7;
  const int n0 = (k8 & (nb - 1)) << 7;

  const bf16_t* Bt = p.Bt;
  const float* bias = p.bias;
  if (p.day_ids) {
    int day = p.day_ids[m0 >> 11];      // 2048 rows per batch
    Bt += (long)day * p.bStrideBt;
    if (bias) bias += (long)day * p.bStrideBias;
  }
  const int K = p.K;
  const int srow = tid >> 2;                      // 0..63
  const int sc = ((tid & 3) - (tid >> 4)) & 3;    // global chunk this lane stages
  const int sk = sc << 3;                         // element offset of that chunk

  int ar0 = m0 + srow, ar1 = m0 + srow + 64;
  if (p.revA) {
    int t0 = ar0 & (T_-1); ar0 = ar0 - t0 + (T_-1 - t0);
    int t1 = ar1 & (T_-1); ar1 = ar1 - t1 + (T_-1 - t1);
  }
  const bf16_t* aP0 = p.A + (long)ar0 * K + sk;
  const bf16_t* aP1 = p.A + (long)ar1 * K + sk;
  const bf16_t* bP0 = Bt + (long)(n0 + srow) * K + sk;
  const bf16_t* bP1 = bP0 + (long)64 * K;

  char* aL = (char*)As + wave * 1024;   // +4096: rows 64-127; +8192: buffer 1
  char* bL = (char*)Bs + wave * 1024;

  f32x4 acc[4][4] = {};   // [im][in]
  const int mw = ((wave >> 1) << 6), nw = ((wave & 1) << 6);
  const int fr = lane & 15;
  const int foff = (((lane >> 4) + (fr >> 2)) & 3) << 4;  // swizzled chunk byte off

  // prologue: stage tile 0 into buffer 0
  gll16(aP0, aL);
  gll16(aP1, aL + 4096);
  gll16(bP0, bL);
  gll16(bP1, bL + 4096);
  __syncthreads();

  const int nIter = K >> 5;
  for (int it = 0; it < nIter; ++it) {
    const int cur = (it & 1) << 13;     // byte offset of current buffer
    const int nxt = cur ^ 8192;
    if (it + 1 < nIter) {               // prefetch next tile into other buffer
      const int k1 = (it + 1) << 5;
      gll16(aP0 + k1, aL + nxt);
      gll16(aP1 + k1, aL + nxt + 4096);
      gll16(bP0 + k1, bL + nxt);
      gll16(bP1 + k1, bL + nxt + 4096);
    }
    bf16x8 af[4], bfr[4];
#pragma unroll
    for (int i = 0; i < 4; i++)
      af[i] = *(const bf16x8*)((char*)As + cur + (mw + i*16 + fr)*64 + foff);
#pragma unroll
    for (int j = 0; j < 4; j++)
      bfr[j] = *(const bf16x8*)((char*)Bs + cur + (nw + j*16 + fr)*64 + foff);
#pragma unroll
    for (int im = 0; im < 4; im++)
#pragma unroll
      for (int in = 0; in < 4; in++)
        acc[im][in] = __builtin_amdgcn_mfma_f32_16x16x32_bf16(bfr[in], af[im], acc[im][in], 0, 0, 0);
    __syncthreads();   // drains prefetch vmcnt AFTER compute; guards cur reuse
  }

  // Lane's C coords: row m = m0+mw+im*16+cn, cols n = n0+nw+in*16+rq+(0..3)
  const int cn = lane & 15, rq = (lane >> 4) << 2;
  f32x4 csum[4];   // act==3: per-lane column partial sums over this wave's 64 rows
#pragma unroll
  for (int in = 0; in < 4; in++) csum[in] = (f32x4){0.f,0.f,0.f,0.f};

#pragma unroll
  for (int im = 0; im < 4; im++) {
    int gr = m0 + mw + im*16 + cn;
    int orow = gr;
    if (p.revC) { int t = gr & (T_-1); orow = gr - t + (T_-1 - t); }
    long rowOff = (long)orow * p.ldout + p.colOff;
#pragma unroll
    for (int in = 0; in < 4; in++) {
      int colb = n0 + nw + in*16 + rq;
      f32x4 v = acc[im][in];
      if (bias) {
        f32x4 bv = *(const f32x4*)(bias + colb);
        v = v + bv;
      }
      if (p.act == 1) {
#pragma unroll
        for (int r = 0; r < 4; r++) v[r] = v[r] / (1.f + fabsf(v[r]));   // softsign
      } else if (p.act >= 2) {                                           // softplus
#pragma unroll
        for (int r = 0; r < 4; r++) {
          float e = __expf(-fabsf(v[r]));
          v[r] = fmaxf(v[r], 0.f) + __logf(1.f + e);
        }
      }
      if (p.act == 3) csum[in] = csum[in] + v;
      if (p.outB) {
        bf16x4 o;
#pragma unroll
        for (int r = 0; r < 4; r++) o[r] = (bf16_t)v[r];
        *(bf16x4*)(p.outB + rowOff + colb) = o;
      }
      if (p.outF) {
#pragma unroll
        for (int r = 0; r < 4; r++) {
          int col = colb + r;
          if (col < p.nValid) p.outF[rowOff + col] = v[r];
        }
      }
    }
  }

  if (p.act == 3) {
    // reduce csum across the 16 cn lanes (lane bits 0-3), then lane cn==0 writes
#pragma unroll
    for (int in = 0; in < 4; in++) {
#pragma unroll
      for (int b = 1; b < 16; b <<= 1) {
#pragma unroll
        for (int r = 0; r < 4; r++) csum[in][r] += __shfl_xor(csum[in][r], b);
      }
    }
    if (cn == 0) {
      int chunk = (m0 + mw) >> 6;
#pragma unroll
      for (int in = 0; in < 4; in++)
        *(f32x4*)(p.sums + (long)chunk * INNER_ + n0 + nw + in*16 + rq) = csum[in];
    }
  }
}

// ---------------- LayerNorm (one wave per 256-wide row), bf16 in/out -------------
__global__ __launch_bounds__(256)
void ln_kernel(const bf16_t* in, const bf16_t* resid, const float* s, const float* bb,
               bf16_t* outB, int doSilu) {
  int row = (blockIdx.x << 2) + (threadIdx.x >> 6);
  int lane = threadIdx.x & 63;
  long base = (long)row * D_ + (lane << 2);
  bf16x4 iv = *(const bf16x4*)(in + base);
  float v[4];
#pragma unroll
  for (int k = 0; k < 4; k++) v[k] = (float)iv[k];
  if (resid) {
    bf16x4 rv = *(const bf16x4*)(resid + base);
#pragma unroll
    for (int k = 0; k < 4; k++) v[k] += (float)rv[k];
  }
  float s1 = v[0] + v[1] + v[2] + v[3];
  float s2 = v[0]*v[0] + v[1]*v[1] + v[2]*v[2] + v[3]*v[3];
#pragma unroll
  for (int off = 1; off < 64; off <<= 1) {
    s1 += __shfl_xor(s1, off);
    s2 += __shfl_xor(s2, off);
  }
  float mean = s1 * (1.f / D_);
  float var = s2 * (1.f / D_) - mean * mean;
  float inv = rsqrtf(var + 1e-5f);
  f32x4 sv = *(const f32x4*)(s + (lane << 2));
  f32x4 bv = *(const f32x4*)(bb + (lane << 2));
  bf16x4 ov;
#pragma unroll
  for (int k = 0; k < 4; k++) {
    float val = (v[k] - mean) * inv * sv[k] + bv[k];
    if (doSilu) val = val / (1.f + __expf(-val));
    ov[k] = (bf16_t)val;
  }
  *(bf16x4*)(outB + base) = ov;
}

// ---------------- depthwise conv (taps t-2..t+1) + bias + silu, x8 vectorized ----
__global__ __launch_bounds__(256)
void conv_kernel(const bf16_t* xz, const float* K4, const float* cb, bf16_t* xc) {
  long idx = (long)blockIdx.x * 256 + threadIdx.x;
  int ch0 = ((int)(idx & 63)) << 3;
  long bt = idx >> 6;
  int t = (int)(bt & (T_-1));
  const bf16_t* base = xz + bt * (2*INNER_) + ch0;
  bf16x8 r0, r1, r2, r3;
  r2 = *(const bf16x8*)(base);
#pragma unroll
  for (int k = 0; k < 8; k++) { r0[k] = (bf16_t)0.f; r1[k] = (bf16_t)0.f; r3[k] = (bf16_t)0.f; }
  if (t >= 2) r0 = *(const bf16x8*)(base - 2*(2*INNER_));
  if (t >= 1) r1 = *(const bf16x8*)(base - (2*INNER_));
  if (t < T_-1) r3 = *(const bf16x8*)(base + (2*INNER_));
  bf16x8 o8;
#pragma unroll
  for (int k = 0; k < 8; k++) {
    f32x4 kk = *(const f32x4*)(K4 + ((ch0 + k) << 2));
    float a = cb[ch0 + k] + (float)r0[k]*kk[0] + (float)r1[k]*kk[1]
            + (float)r2[k]*kk[2] + (float)r3[k]*kk[3];
    o8[k] = (bf16_t)(a / (1.f + __expf(-a)));
  }
  *(bf16x8*)(xc + bt * INNER_ + ch0) = o8;
}

// y = xc * w * silu(z) in place over xc; chunk-prefix computed on the fly ----------
__global__ __launch_bounds__(256)
void y_kernel(const bf16_t* dt, const bf16_t* xz, bf16_t* xc, const float* sums) {
  int bc = blockIdx.x * 4 + (threadIdx.x >> 6);
  int b = bc >> 5;           // NCHUNK_ = 32
  int c = bc & 31;
  int ch0 = (threadIdx.x & 63) << 3;
  float acc[8] = {};
  const float* sp = sums + (long)b * NCHUNK_ * INNER_ + ch0;
  for (int cp = 0; cp < c; cp++) {
#pragma unroll
    for (int k = 0; k < 8; k++) acc[k] += sp[(long)cp * INNER_ + k];
  }
  long bt0 = (long)bc * CHUNK_;
  for (int i = 0; i < CHUNK_; i++) {
    long bt = bt0 + i;
    bf16x8 d8 = *(const bf16x8*)(dt + bt * INNER_ + ch0);
    bf16x8 z8 = *(const bf16x8*)(xz + bt * (2*INNER_) + INNER_ + ch0);
    bf16x8 x8 = *(const bf16x8*)(xc + bt * INNER_ + ch0);
    bf16x8 o8;
#pragma unroll
    for (int k = 0; k < 8; k++) {
      acc[k] += (float)d8[k];
      float w = __expf(-0.1f * acc[k]);
      float zz = (float)z8[k];
      float sz = zz / (1.f + __expf(-zz));
      o8[k] = (bf16_t)((float)x8[k] * w * sz);
    }
    *(bf16x8*)(xc + bt * INNER_ + ch0) = o8;
  }
}

// ---------------- log_softmax over 41 (one wave per row) -------------------------
__global__ __launch_bounds__(256)
void lsm_kernel(const float* logits, float* out) {
  int row = (blockIdx.x << 2) + (threadIdx.x >> 6);
  int lane = threadIdx.x & 63;
  float v = (lane < 41) ? logits[(long)row * 41 + lane] : -3.4e38f;
  float m = v;
#pragma unroll
  for (int off = 1; off < 64; off <<= 1) m = fmaxf(m, __shfl_xor(m, off));
  float e = (lane < 41) ? __expf(v - m) : 0.f;
  float ssum = e;
#pragma unroll
  for (int off = 1; off < 64; off <<= 1) ssum += __shfl_xor(ssum, off);
  float ls = __logf(ssum);
  if (lane < 41) out[(long)row * 41 + lane] = v - m - ls;
}

// ---------------- fp32 (R,C) -> bf16 (C,R) transpose, batched via z --------------
__global__ void tconv_kernel(const float* in, bf16_t* out, int R, int C) {
  __shared__ float tile[32][33];
  const float* ip = in + (long)blockIdx.z * R * C;
  bf16_t* op = out + (long)blockIdx.z * R * C;
  int c0 = blockIdx.x << 5, r0 = blockIdx.y << 5;
  int tx = threadIdx.x, ty = threadIdx.y;
  for (int i = ty; i < 32; i += 8) {
    int r = r0 + i, c = c0 + tx;
    tile[i][tx] = (r < R && c < C) ? ip[(long)r * C + c] : 0.f;
  }
  __syncthreads();
  for (int i = ty; i < 32; i += 8) {
    int c = c0 + i, r = r0 + tx;
    if (c < C && r < R) op[(long)c * R + r] = (bf16_t)tile[tx][i];
  }
}

__global__ void cvt_kernel(const float* in, bf16_t* out, long n) {
  long i = ((long)blockIdx.x * blockDim.x + threadIdx.x) << 3;
  if (i >= n) return;
  f32x4 a = *(const f32x4*)(in + i);
  f32x4 b = *(const f32x4*)(in + i + 4);
  bf16x8 o;
#pragma unroll
  for (int k = 0; k < 4; k++) { o[k] = (bf16_t)a[k]; o[k+4] = (bf16_t)b[k]; }
  *(bf16x8*)(out + i) = o;
}

__global__ void zfill_kernel(bf16_t* p, int n) {
  int i = blockIdx.x * 256 + threadIdx.x;
  if (i < n) p[i] = (bf16_t)0.f;
}

extern "C" void kernel_launch(void* const* d_in, const int* in_sizes, int n_in,
                              void* d_out, int out_size, void* d_ws, size_t ws_size,
                              hipStream_t stream) {
  (void)in_sizes; (void)n_in; (void)out_size;
  const float* x         = (const float*)d_in[0];
  const int*   day_ids   = (const int*)d_in[1];
  const float* adapter_W = (const float*)d_in[2];
  const float* adapter_b = (const float*)d_in[3];
  const float* cW1       = (const float*)d_in[4];
  const float* cb1       = (const float*)d_in[5];
  const float* cln1_s    = (const float*)d_in[6];
  const float* cln1_b    = (const float*)d_in[7];
  const float* cW2       = (const float*)d_in[8];
  const float* cb2       = (const float*)d_in[9];
  const float* cln2_s    = (const float*)d_in[10];
  const float* cln2_b    = (const float*)d_in[11];
  const float* m_in      = (const float*)d_in[12];
  const float* m_convK   = (const float*)d_in[13];
  const float* m_convB   = (const float*)d_in[14];
  const float* m_dtW     = (const float*)d_in[15];
  const float* m_dtB     = (const float*)d_in[16];
  const float* m_out     = (const float*)d_in[17];
  const float* proj_W    = (const float*)d_in[18];
  const float* proj_b    = (const float*)d_in[19];
  const float* norm_s    = (const float*)d_in[20];
  const float* norm_b    = (const float*)d_in[21];
  const float* outW      = (const float*)d_in[22];
  const float* outb      = (const float*)d_in[23];
  float* out = (float*)d_out;

  char* ws = (char*)d_ws;
  size_t off = 0;
  auto alloc = [&](size_t bytes) -> char* {
    char* p = ws + off;
    off += (bytes + 255) & ~(size_t)255;
    return p;
  };
  // ---- fixed: transposed bf16 weights (~33 MB) ----
  bf16_t* adapterT = (bf16_t*)alloc((size_t)45*512*512*2);
  bf16_t* cW1T     = (bf16_t*)alloc((size_t)256*512*2);
  bf16_t* cW2T     = (bf16_t*)alloc((size_t)256*256*2);
  bf16_t* m_inT    = (bf16_t*)alloc((size_t)6*1024*256*2);
  bf16_t* m_dtWT   = (bf16_t*)alloc((size_t)6*512*512*2);
  bf16_t* m_outT   = (bf16_t*)alloc((size_t)6*256*512*2);
  bf16_t* projT    = (bf16_t*)alloc((size_t)3*256*512*2);
  bf16_t* outWT    = (bf16_t*)alloc((size_t)128*256*2);

  // ---- adaptive group size: largest Bg whose regions fit ws_size ----
  int Bg = 0;
  {
    const int cands[6] = {32, 16, 8, 4, 2, 1};
    for (int ci = 0; ci < 6; ci++) {
      int c = cands[ci];
      size_t Mg = (size_t)c * T_;
      size_t need = Mg*2048 + 3*(Mg*1024) + Mg*512 + (size_t)c*NCHUNK_*INNER_*4
                    + 8*256;  // alignment slack
      if (off + need <= ws_size) { Bg = c; break; }
    }
  }
  if (Bg == 0) return;  // workspace too small to run at all
  const size_t Mg = (size_t)Bg * T_;
  char*  xzR  = alloc(Mg * 2048);          // xz (Mg x 1024 bf16); also x_bf, logits
  char*  xcR  = alloc(Mg * 1024);          // xc / y (Mg x 512 bf16); also h0
  char*  dtR  = alloc(Mg * 1024);          // dt (Mg x 512 bf16); also tmp pre-LN bf16
  char*  swR  = alloc(Mg * 1024);          // swcat (Mg x 512 bf16); also h1
  bf16_t* hG  = (bf16_t*)alloc(Mg * 512);  // h (Mg x 256 bf16)
  float* sums = (float*)alloc((size_t)Bg * NCHUNK_ * INNER_ * 4);

  // ---- weight conversion/transpose (once) ----
  zfill_kernel<<<128, 256, 0, stream>>>(outWT, 128*256);
  dim3 tb(32, 8);
  tconv_kernel<<<dim3(16,16,45), tb, 0, stream>>>(adapter_W, adapterT, 512, 512);
  tconv_kernel<<<dim3(8,16,1),  tb, 0, stream>>>(cW1,  cW1T,  512, 256);
  tconv_kernel<<<dim3(8,8,1),   tb, 0, stream>>>(cW2,  cW2T,  256, 256);
  tconv_kernel<<<dim3(32,8,6),  tb, 0, stream>>>(m_in, m_inT, 256, 1024);
  tconv_kernel<<<dim3(16,16,6), tb, 0, stream>>>(m_dtW, m_dtWT, 512, 512);
  tconv_kernel<<<dim3(8,16,6),  tb, 0, stream>>>(m_out, m_outT, 512, 256);
  tconv_kernel<<<dim3(8,16,3),  tb, 0, stream>>>(proj_W, projT, 512, 256);
  tconv_kernel<<<dim3(2,8,1),   tb, 0, stream>>>(outW, outWT, 256, 41);

  auto gemm = [&](const bf16_t* A, const bf16_t* Bt, const float* bias,
                  float* outF, bf16_t* outB, int K, int N, int ldout, int colOff,
                  int act, int revA, int revC, const int* days, long bsBt, int bsBias,
                  int nValid, float* sumsP) {
    GemmP p;
    p.A = A; p.Bt = Bt; p.bias = bias; p.outF = outF; p.outB = outB; p.sums = sumsP;
    p.day_ids = days; p.bStrideBt = bsBt; p.bStrideBias = bsBias;
    p.K = K; p.N = N; p.ldout = ldout; p.colOff = colOff;
    p.act = act; p.revA = revA; p.revC = revC; p.nValid = nValid;
    gemm_kernel<<<dim3((unsigned)((Mg/128) * (N/128))), 256, 0, stream>>>(p);
  };

  for (int b0 = 0; b0 < B_; b0 += Bg) {
    const float* xg = x + (size_t)b0 * T_ * 512;

    // ---- x -> bf16 ----
    bf16_t* x_bf = (bf16_t*)xzR;
    cvt_kernel<<<(unsigned)(Mg/4), 256, 0, stream>>>(xg, x_bf, (long)Mg*512);

    // ---- adapter: h0 = softsign(x @ W[day] + b[day]) ----
    bf16_t* h0 = (bf16_t*)xcR;
    gemm(x_bf, adapterT, adapter_b, nullptr, h0, 512, 512, 512, 0, /*act*/1, 0, 0,
         day_ids + b0, (long)512*512, 512, 512, nullptr);

    // ---- h1 = silu(LN(h0 @ cW1 + cb1)) ----
    bf16_t* tmpB = (bf16_t*)dtR;
    gemm(h0, cW1T, cb1, nullptr, tmpB, 512, 256, 256, 0, 0, 0, 0, nullptr, 0, 0, 256, nullptr);
    bf16_t* h1 = (bf16_t*)swR;
    ln_kernel<<<(unsigned)(Mg/4), 256, 0, stream>>>(tmpB, nullptr, cln1_s, cln1_b, h1, 1);

    // ---- h = silu(LN(h1 @ cW2 + cb2)) ----
    gemm(h1, cW2T, cb2, nullptr, tmpB, 256, 256, 256, 0, 0, 0, 0, nullptr, 0, 0, 256, nullptr);
    ln_kernel<<<(unsigned)(Mg/4), 256, 0, stream>>>(tmpB, nullptr, cln2_s, cln2_b, hG, 1);

    bf16_t* xz    = (bf16_t*)xzR;
    bf16_t* xc    = (bf16_t*)xcR;
    bf16_t* dt    = (bf16_t*)dtR;
    bf16_t* swcat = (bf16_t*)swR;

    for (int l = 0; l < L_; l++) {
      for (int dir = 0; dir < 2; dir++) {
        int ld = l*2 + dir;
        // xz = h @ Win (reversed read of h for dir=1)
        gemm(hG, m_inT + (size_t)ld*1024*256, nullptr, nullptr, xz,
             256, 1024, 1024, 0, 0, /*revA*/dir, 0, nullptr, 0, 0, 1024, nullptr);
        // xc = silu(dwconv(xi) + convB)
        conv_kernel<<<(unsigned)(Mg/4), 256, 0, stream>>>(
            xz, m_convK + (size_t)ld*512*4, m_convB + (size_t)ld*512, xc);
        // dt = softplus(xc @ dtW + dtB); epilogue also writes per-chunk col sums
        gemm(xc, m_dtWT + (size_t)ld*512*512, m_dtB + (size_t)ld*512, nullptr, dt,
             512, 512, 512, 0, /*act*/3, 0, 0, nullptr, 0, 0, 512, sums);
        // w = exp(-0.1*cumsum(dt)); y = xc * w * silu(z)   (in place over xc)
        y_kernel<<<(unsigned)(Bg*8), 256, 0, stream>>>(dt, xz, xc, sums);
        // swcat[:, dir*256:...] = y @ Wout (store reversed for dir=1)
        gemm(xc, m_outT + (size_t)ld*256*512, nullptr, nullptr, swcat,
             512, 256, 512, dir*256, 0, 0, /*revC*/dir, nullptr, 0, 0, 256, nullptr);
      }
      // combined = swcat @ proj_W + proj_b; h = LN(h + combined)
      bf16_t* tmpB2 = (bf16_t*)dtR;
      gemm(swcat, projT + (size_t)l*256*512, proj_b + (size_t)l*256, nullptr, tmpB2,
           512, 256, 256, 0, 0, 0, 0, nullptr, 0, 0, 256, nullptr);
      ln_kernel<<<(unsigned)(Mg/4), 256, 0, stream>>>(tmpB2, hG, norm_s + (size_t)l*256,
                                                      norm_b + (size_t)l*256, hG, 0);
    }

    // ---- logits + log_softmax ----
    float* logits = (float*)xzR;
    gemm(hG, outWT, outb, logits, nullptr, 256, 128, 41, 0, 0, 0, 0,
         nullptr, 0, 0, 41, nullptr);
    lsm_kernel<<<(unsigned)(Mg/4), 256, 0, stream>>>(logits, out + (size_t)b0 * T_ * 41);
  }
}

// Round 7
// 2412.563 us; speedup vs baseline: 1.4515x; 1.0542x over previous
//
#include <hip/hip_runtime.h>
#include <hip/hip_bf16.h>
#include <cstdint>
#include <math.h>

typedef __bf16 bf16_t;
typedef bf16_t bf16x8 __attribute__((ext_vector_type(8)));
typedef bf16_t bf16x4 __attribute__((ext_vector_type(4)));
typedef float f32x4 __attribute__((ext_vector_type(4)));

#define B_ 32
#define T_ 2048
#define D_ 256
#define INNER_ 512
#define L_ 3
#define CHUNK_ 64
#define NCHUNK_ (T_/CHUNK_) // 32

typedef const __attribute__((address_space(1))) void* gas_t;
typedef __attribute__((address_space(3))) void* las_t;
__device__ __forceinline__ void gll16(const void* g, void* l) {
  __builtin_amdgcn_global_load_lds((gas_t)g, (las_t)l, 16, 0, 0);
}

struct GemmP {
  const bf16_t* A;
  const bf16_t* Bt;
  const float* bias;
  float* outF;
  bf16_t* outB;
  float* sums;          // act==3: per-chunk column sums of the activated output
  const int* day_ids;   // already offset by group base batch
  long bStrideBt;
  int bStrideBias;
  int K, N, ldout, colOff, act, revA, revC, nValid;
};

// C-tile LDS swizzle: 128 rows x 256 B; xor by (row&7)<<4 breaks the 256-B row
// stride bank aliasing (writes <=4-way, reads 2-way). Low 4 bits untouched.
__device__ __forceinline__ int csw(int row, int colByte) {
  return (row << 8) + (colByte ^ ((row & 7) << 4));
}

// ---------------- GEMM: C = A(MxK) * Bt(NxK)^T, bf16 in, fp32 acc ----------------
// XCD-aware 1-D grid swizzle (bid%8 -> XCD): A-tiles re-served from XCD-local L2
// across N-column blocks. Double-buffered LDS staging via global_load_lds with
// source-side chunk swizzle. MFMA operand order (b_frag, a_frag): n on D's reg
// axis. Epilogue: acc -> LDS C-tile (reusing the dead staging buffers) ->
// contiguous 256-B-per-row global_store_dwordx4.
__global__ __launch_bounds__(256, 4)
void gemm_kernel(GemmP p) {
  __shared__ char smem[32768];      // staging: As=smem, Bs=smem+16K; epilogue: C-tile
  bf16_t* As = (bf16_t*)smem;
  bf16_t* Bs = (bf16_t*)(smem + 16384);
  const int tid = threadIdx.x;
  const int wave = tid >> 6, lane = tid & 63;

  // ---- swizzled block decode ----
  const int nb = p.N >> 7;                 // N-blocks (1,2,4,8)
  const int nbs = __builtin_ctz(nb);
  const int c8 = blockIdx.x & 7;           // XCD id under round-robin
  const int k8 = blockIdx.x >> 3;
  const int mGrp = (gridDim.x >> 3) >> nbs;  // M-tiles per XCD
  const int m0 = (c8 * mGrp + (k8 >> nbs)) << 7;
  const int n0 = (k8 & (nb - 1)) << 7;

  const bf16_t* Bt = p.Bt;
  const float* bias = p.bias;
  if (p.day_ids) {
    int day = p.day_ids[m0 >> 11];      // 2048 rows per batch
    Bt += (long)day * p.bStrideBt;
    if (bias) bias += (long)day * p.bStrideBias;
  }
  const int K = p.K;
  const int srow = tid >> 2;                      // 0..63
  const int sc = ((tid & 3) - (tid >> 4)) & 3;    // global chunk this lane stages
  const int sk = sc << 3;                         // element offset of that chunk

  int ar0 = m0 + srow, ar1 = m0 + srow + 64;
  if (p.revA) {
    int t0 = ar0 & (T_-1); ar0 = ar0 - t0 + (T_-1 - t0);
    int t1 = ar1 & (T_-1); ar1 = ar1 - t1 + (T_-1 - t1);
  }
  const bf16_t* aP0 = p.A + (long)ar0 * K + sk;
  const bf16_t* aP1 = p.A + (long)ar1 * K + sk;
  const bf16_t* bP0 = Bt + (long)(n0 + srow) * K + sk;
  const bf16_t* bP1 = bP0 + (long)64 * K;

  char* aL = (char*)As + wave * 1024;   // +4096: rows 64-127; +8192: buffer 1
  char* bL = (char*)Bs + wave * 1024;

  f32x4 acc[4][4] = {};   // [im][in]
  const int mw = ((wave >> 1) << 6), nw = ((wave & 1) << 6);
  const int fr = lane & 15;
  const int foff = (((lane >> 4) + (fr >> 2)) & 3) << 4;  // swizzled chunk byte off

  // prologue: stage tile 0 into buffer 0
  gll16(aP0, aL);
  gll16(aP1, aL + 4096);
  gll16(bP0, bL);
  gll16(bP1, bL + 4096);
  __syncthreads();

  const int nIter = K >> 5;
  for (int it = 0; it < nIter; ++it) {
    const int cur = (it & 1) << 13;     // byte offset of current buffer
    const int nxt = cur ^ 8192;
    if (it + 1 < nIter) {               // prefetch next tile into other buffer
      const int k1 = (it + 1) << 5;
      gll16(aP0 + k1, aL + nxt);
      gll16(aP1 + k1, aL + nxt + 4096);
      gll16(bP0 + k1, bL + nxt);
      gll16(bP1 + k1, bL + nxt + 4096);
    }
    bf16x8 af[4], bfr[4];
#pragma unroll
    for (int i = 0; i < 4; i++)
      af[i] = *(const bf16x8*)((char*)As + cur + (mw + i*16 + fr)*64 + foff);
#pragma unroll
    for (int j = 0; j < 4; j++)
      bfr[j] = *(const bf16x8*)((char*)Bs + cur + (nw + j*16 + fr)*64 + foff);
#pragma unroll
    for (int im = 0; im < 4; im++)
#pragma unroll
      for (int in = 0; in < 4; in++)
        acc[im][in] = __builtin_amdgcn_mfma_f32_16x16x32_bf16(bfr[in], af[im], acc[im][in], 0, 0, 0);
    __syncthreads();   // drains prefetch vmcnt; also frees LDS for the epilogue
  }

  // Lane's C coords: row m = m0+mw+im*16+cn, cols n = n0+nw+in*16+rq+(0..3)
  const int cn = lane & 15, rq = (lane >> 4) << 2;
  f32x4 csum[4];   // act==3: per-lane column partial sums over this wave's 64 rows
#pragma unroll
  for (int in = 0; in < 4; in++) csum[in] = (f32x4){0.f,0.f,0.f,0.f};

#pragma unroll
  for (int im = 0; im < 4; im++) {
    int trow = mw + im*16 + cn;          // row within the 128-row tile
#pragma unroll
    for (int in = 0; in < 4; in++) {
      int tcolB = (nw + in*16 + rq) << 1;  // byte col within the 256-B tile row
      int colb = n0 + nw + in*16 + rq;
      f32x4 v = acc[im][in];
      if (bias) {
        f32x4 bv = *(const f32x4*)(bias + colb);
        v = v + bv;
      }
      if (p.act == 1) {
#pragma unroll
        for (int r = 0; r < 4; r++) v[r] = v[r] / (1.f + fabsf(v[r]));   // softsign
      } else if (p.act >= 2) {                                           // softplus
#pragma unroll
        for (int r = 0; r < 4; r++) {
          float e = __expf(-fabsf(v[r]));
          v[r] = fmaxf(v[r], 0.f) + __logf(1.f + e);
        }
      }
      if (p.act == 3) csum[in] = csum[in] + v;
      if (p.outB) {
        bf16x4 o;
#pragma unroll
        for (int r = 0; r < 4; r++) o[r] = (bf16_t)v[r];
        *(bf16x4*)(smem + csw(trow, tcolB)) = o;
      }
      if (p.outF) {
        int gr = m0 + trow;
        int orow = gr;
        if (p.revC) { int t = gr & (T_-1); orow = gr - t + (T_-1 - t); }
        long rowOff = (long)orow * p.ldout + p.colOff;
#pragma unroll
        for (int r = 0; r < 4; r++) {
          int col = colb + r;
          if (col < p.nValid) p.outF[rowOff + col] = v[r];
        }
      }
    }
  }

  if (p.act == 3) {
    // reduce csum across the 16 cn lanes (lane bits 0-3), then lane cn==0 writes
#pragma unroll
    for (int in = 0; in < 4; in++) {
#pragma unroll
      for (int b = 1; b < 16; b <<= 1) {
#pragma unroll
        for (int r = 0; r < 4; r++) csum[in][r] += __shfl_xor(csum[in][r], b);
      }
    }
    if (cn == 0) {
      int chunk = (m0 + mw) >> 6;
#pragma unroll
      for (int in = 0; in < 4; in++)
        *(f32x4*)(p.sums + (long)chunk * INNER_ + n0 + nw + in*16 + rq) = csum[in];
    }
  }

  if (p.outB) {
    __syncthreads();
    // each iter: 16 rows x (16 lanes x 16 B = full 256-B contiguous row)
    const int rsub = tid >> 4;           // 0..15
    const int cb16 = (tid & 15) << 4;    // byte col, 16-B chunk
#pragma unroll
    for (int itr = 0; itr < 8; ++itr) {
      int trow = (itr << 4) + rsub;
      bf16x8 val = *(const bf16x8*)(smem + csw(trow, cb16));
      int gr = m0 + trow;
      int orow = gr;
      if (p.revC) { int t = gr & (T_-1); orow = gr - t + (T_-1 - t); }
      long off = (long)orow * p.ldout + p.colOff + n0 + (cb16 >> 1);
      *(bf16x8*)(p.outB + off) = val;
    }
  }
}

// ---------------- LayerNorm (one wave per 256-wide row), bf16 in/out -------------
__global__ __launch_bounds__(256)
void ln_kernel(const bf16_t* in, const bf16_t* resid, const float* s, const float* bb,
               bf16_t* outB, int doSilu) {
  int row = (blockIdx.x << 2) + (threadIdx.x >> 6);
  int lane = threadIdx.x & 63;
  long base = (long)row * D_ + (lane << 2);
  bf16x4 iv = *(const bf16x4*)(in + base);
  float v[4];
#pragma unroll
  for (int k = 0; k < 4; k++) v[k] = (float)iv[k];
  if (resid) {
    bf16x4 rv = *(const bf16x4*)(resid + base);
#pragma unroll
    for (int k = 0; k < 4; k++) v[k] += (float)rv[k];
  }
  float s1 = v[0] + v[1] + v[2] + v[3];
  float s2 = v[0]*v[0] + v[1]*v[1] + v[2]*v[2] + v[3]*v[3];
#pragma unroll
  for (int off = 1; off < 64; off <<= 1) {
    s1 += __shfl_xor(s1, off);
    s2 += __shfl_xor(s2, off);
  }
  float mean = s1 * (1.f / D_);
  float var = s2 * (1.f / D_) - mean * mean;
  float inv = rsqrtf(var + 1e-5f);
  f32x4 sv = *(const f32x4*)(s + (lane << 2));
  f32x4 bv = *(const f32x4*)(bb + (lane << 2));
  bf16x4 ov;
#pragma unroll
  for (int k = 0; k < 4; k++) {
    float val = (v[k] - mean) * inv * sv[k] + bv[k];
    if (doSilu) val = val / (1.f + __expf(-val));
    ov[k] = (bf16_t)val;
  }
  *(bf16x4*)(outB + base) = ov;
}

// ---------------- depthwise conv (taps t-2..t+1) + bias + silu, x8 vectorized ----
__global__ __launch_bounds__(256)
void conv_kernel(const bf16_t* xz, const float* K4, const float* cb, bf16_t* xc) {
  long idx = (long)blockIdx.x * 256 + threadIdx.x;
  int ch0 = ((int)(idx & 63)) << 3;
  long bt = idx >> 6;
  int t = (int)(bt & (T_-1));
  const bf16_t* base = xz + bt * (2*INNER_) + ch0;
  bf16x8 r0, r1, r2, r3;
  r2 = *(const bf16x8*)(base);
#pragma unroll
  for (int k = 0; k < 8; k++) { r0[k] = (bf16_t)0.f; r1[k] = (bf16_t)0.f; r3[k] = (bf16_t)0.f; }
  if (t >= 2) r0 = *(const bf16x8*)(base - 2*(2*INNER_));
  if (t >= 1) r1 = *(const bf16x8*)(base - (2*INNER_));
  if (t < T_-1) r3 = *(const bf16x8*)(base + (2*INNER_));
  bf16x8 o8;
#pragma unroll
  for (int k = 0; k < 8; k++) {
    f32x4 kk = *(const f32x4*)(K4 + ((ch0 + k) << 2));
    float a = cb[ch0 + k] + (float)r0[k]*kk[0] + (float)r1[k]*kk[1]
            + (float)r2[k]*kk[2] + (float)r3[k]*kk[3];
    o8[k] = (bf16_t)(a / (1.f + __expf(-a)));
  }
  *(bf16x8*)(xc + bt * INNER_ + ch0) = o8;
}

// y = xc * w * silu(z) in place over xc; chunk-prefix computed on the fly ----------
__global__ __launch_bounds__(256)
void y_kernel(const bf16_t* dt, const bf16_t* xz, bf16_t* xc, const float* sums) {
  int bc = blockIdx.x * 4 + (threadIdx.x >> 6);
  int b = bc >> 5;           // NCHUNK_ = 32
  int c = bc & 31;
  int ch0 = (threadIdx.x & 63) << 3;
  float acc[8] = {};
  const float* sp = sums + (long)b * NCHUNK_ * INNER_ + ch0;
  for (int cp = 0; cp < c; cp++) {
#pragma unroll
    for (int k = 0; k < 8; k++) acc[k] += sp[(long)cp * INNER_ + k];
  }
  long bt0 = (long)bc * CHUNK_;
  for (int i = 0; i < CHUNK_; i++) {
    long bt = bt0 + i;
    bf16x8 d8 = *(const bf16x8*)(dt + bt * INNER_ + ch0);
    bf16x8 z8 = *(const bf16x8*)(xz + bt * (2*INNER_) + INNER_ + ch0);
    bf16x8 x8 = *(const bf16x8*)(xc + bt * INNER_ + ch0);
    bf16x8 o8;
#pragma unroll
    for (int k = 0; k < 8; k++) {
      acc[k] += (float)d8[k];
      float w = __expf(-0.1f * acc[k]);
      float zz = (float)z8[k];
      float sz = zz / (1.f + __expf(-zz));
      o8[k] = (bf16_t)((float)x8[k] * w * sz);
    }
    *(bf16x8*)(xc + bt * INNER_ + ch0) = o8;
  }
}

// ---------------- log_softmax over 41 (one wave per row) -------------------------
__global__ __launch_bounds__(256)
void lsm_kernel(const float* logits, float* out) {
  int row = (blockIdx.x << 2) + (threadIdx.x >> 6);
  int lane = threadIdx.x & 63;
  float v = (lane < 41) ? logits[(long)row * 41 + lane] : -3.4e38f;
  float m = v;
#pragma unroll
  for (int off = 1; off < 64; off <<= 1) m = fmaxf(m, __shfl_xor(m, off));
  float e = (lane < 41) ? __expf(v - m) : 0.f;
  float ssum = e;
#pragma unroll
  for (int off = 1; off < 64; off <<= 1) ssum += __shfl_xor(ssum, off);
  float ls = __logf(ssum);
  if (lane < 41) out[(long)row * 41 + lane] = v - m - ls;
}

// ---------------- fp32 (R,C) -> bf16 (C,R) transpose, batched via z --------------
__global__ void tconv_kernel(const float* in, bf16_t* out, int R, int C) {
  __shared__ float tile[32][33];
  const float* ip = in + (long)blockIdx.z * R * C;
  bf16_t* op = out + (long)blockIdx.z * R * C;
  int c0 = blockIdx.x << 5, r0 = blockIdx.y << 5;
  int tx = threadIdx.x, ty = threadIdx.y;
  for (int i = ty; i < 32; i += 8) {
    int r = r0 + i, c = c0 + tx;
    tile[i][tx] = (r < R && c < C) ? ip[(long)r * C + c] : 0.f;
  }
  __syncthreads();
  for (int i = ty; i < 32; i += 8) {
    int c = c0 + i, r = r0 + tx;
    if (c < C && r < R) op[(long)c * R + r] = (bf16_t)tile[tx][i];
  }
}

__global__ void cvt_kernel(const float* in, bf16_t* out, long n) {
  long i = ((long)blockIdx.x * blockDim.x + threadIdx.x) << 3;
  if (i >= n) return;
  f32x4 a = *(const f32x4*)(in + i);
  f32x4 b = *(const f32x4*)(in + i + 4);
  bf16x8 o;
#pragma unroll
  for (int k = 0; k < 4; k++) { o[k] = (bf16_t)a[k]; o[k+4] = (bf16_t)b[k]; }
  *(bf16x8*)(out + i) = o;
}

__global__ void zfill_kernel(bf16_t* p, int n) {
  int i = blockIdx.x * 256 + threadIdx.x;
  if (i < n) p[i] = (bf16_t)0.f;
}

extern "C" void kernel_launch(void* const* d_in, const int* in_sizes, int n_in,
                              void* d_out, int out_size, void* d_ws, size_t ws_size,
                              hipStream_t stream) {
  (void)in_sizes; (void)n_in; (void)out_size;
  const float* x         = (const float*)d_in[0];
  const int*   day_ids   = (const int*)d_in[1];
  const float* adapter_W = (const float*)d_in[2];
  const float* adapter_b = (const float*)d_in[3];
  const float* cW1       = (const float*)d_in[4];
  const float* cb1       = (const float*)d_in[5];
  const float* cln1_s    = (const float*)d_in[6];
  const float* cln1_b    = (const float*)d_in[7];
  const float* cW2       = (const float*)d_in[8];
  const float* cb2       = (const float*)d_in[9];
  const float* cln2_s    = (const float*)d_in[10];
  const float* cln2_b    = (const float*)d_in[11];
  const float* m_in      = (const float*)d_in[12];
  const float* m_convK   = (const float*)d_in[13];
  const float* m_convB   = (const float*)d_in[14];
  const float* m_dtW     = (const float*)d_in[15];
  const float* m_dtB     = (const float*)d_in[16];
  const float* m_out     = (const float*)d_in[17];
  const float* proj_W    = (const float*)d_in[18];
  const float* proj_b    = (const float*)d_in[19];
  const float* norm_s    = (const float*)d_in[20];
  const float* norm_b    = (const float*)d_in[21];
  const float* outW      = (const float*)d_in[22];
  const float* outb      = (const float*)d_in[23];
  float* out = (float*)d_out;

  char* ws = (char*)d_ws;
  size_t off = 0;
  auto alloc = [&](size_t bytes) -> char* {
    char* p = ws + off;
    off += (bytes + 255) & ~(size_t)255;
    return p;
  };
  // ---- fixed: transposed bf16 weights (~33 MB) ----
  bf16_t* adapterT = (bf16_t*)alloc((size_t)45*512*512*2);
  bf16_t* cW1T     = (bf16_t*)alloc((size_t)256*512*2);
  bf16_t* cW2T     = (bf16_t*)alloc((size_t)256*256*2);
  bf16_t* m_inT    = (bf16_t*)alloc((size_t)6*1024*256*2);
  bf16_t* m_dtWT   = (bf16_t*)alloc((size_t)6*512*512*2);
  bf16_t* m_outT   = (bf16_t*)alloc((size_t)6*256*512*2);
  bf16_t* projT    = (bf16_t*)alloc((size_t)3*256*512*2);
  bf16_t* outWT    = (bf16_t*)alloc((size_t)128*256*2);

  // ---- adaptive group size: largest Bg whose regions fit ws_size ----
  int Bg = 0;
  {
    const int cands[6] = {32, 16, 8, 4, 2, 1};
    for (int ci = 0; ci < 6; ci++) {
      int c = cands[ci];
      size_t Mg = (size_t)c * T_;
      size_t need = Mg*2048 + 3*(Mg*1024) + Mg*512 + (size_t)c*NCHUNK_*INNER_*4
                    + 8*256;  // alignment slack
      if (off + need <= ws_size) { Bg = c; break; }
    }
  }
  if (Bg == 0) return;  // workspace too small to run at all
  const size_t Mg = (size_t)Bg * T_;
  char*  xzR  = alloc(Mg * 2048);          // xz (Mg x 1024 bf16); also x_bf, logits
  char*  xcR  = alloc(Mg * 1024);          // xc / y (Mg x 512 bf16); also h0
  char*  dtR  = alloc(Mg * 1024);          // dt (Mg x 512 bf16); also tmp pre-LN bf16
  char*  swR  = alloc(Mg * 1024);          // swcat (Mg x 512 bf16); also h1
  bf16_t* hG  = (bf16_t*)alloc(Mg * 512);  // h (Mg x 256 bf16)
  float* sums = (float*)alloc((size_t)Bg * NCHUNK_ * INNER_ * 4);

  // ---- weight conversion/transpose (once) ----
  zfill_kernel<<<128, 256, 0, stream>>>(outWT, 128*256);
  dim3 tb(32, 8);
  tconv_kernel<<<dim3(16,16,45), tb, 0, stream>>>(adapter_W, adapterT, 512, 512);
  tconv_kernel<<<dim3(8,16,1),  tb, 0, stream>>>(cW1,  cW1T,  512, 256);
  tconv_kernel<<<dim3(8,8,1),   tb, 0, stream>>>(cW2,  cW2T,  256, 256);
  tconv_kernel<<<dim3(32,8,6),  tb, 0, stream>>>(m_in, m_inT, 256, 1024);
  tconv_kernel<<<dim3(16,16,6), tb, 0, stream>>>(m_dtW, m_dtWT, 512, 512);
  tconv_kernel<<<dim3(8,16,6),  tb, 0, stream>>>(m_out, m_outT, 512, 256);
  tconv_kernel<<<dim3(8,16,3),  tb, 0, stream>>>(proj_W, projT, 512, 256);
  tconv_kernel<<<dim3(2,8,1),   tb, 0, stream>>>(outW, outWT, 256, 41);

  auto gemm = [&](const bf16_t* A, const bf16_t* Bt, const float* bias,
                  float* outF, bf16_t* outB, int K, int N, int ldout, int colOff,
                  int act, int revA, int revC, const int* days, long bsBt, int bsBias,
                  int nValid, float* sumsP) {
    GemmP p;
    p.A = A; p.Bt = Bt; p.bias = bias; p.outF = outF; p.outB = outB; p.sums = sumsP;
    p.day_ids = days; p.bStrideBt = bsBt; p.bStrideBias = bsBias;
    p.K = K; p.N = N; p.ldout = ldout; p.colOff = colOff;
    p.act = act; p.revA = revA; p.revC = revC; p.nValid = nValid;
    gemm_kernel<<<dim3((unsigned)((Mg/128) * (N/128))), 256, 0, stream>>>(p);
  };

  for (int b0 = 0; b0 < B_; b0 += Bg) {
    const float* xg = x + (size_t)b0 * T_ * 512;

    // ---- x -> bf16 ----
    bf16_t* x_bf = (bf16_t*)xzR;
    cvt_kernel<<<(unsigned)(Mg/4), 256, 0, stream>>>(xg, x_bf, (long)Mg*512);

    // ---- adapter: h0 = softsign(x @ W[day] + b[day]) ----
    bf16_t* h0 = (bf16_t*)xcR;
    gemm(x_bf, adapterT, adapter_b, nullptr, h0, 512, 512, 512, 0, /*act*/1, 0, 0,
         day_ids + b0, (long)512*512, 512, 512, nullptr);

    // ---- h1 = silu(LN(h0 @ cW1 + cb1)) ----
    bf16_t* tmpB = (bf16_t*)dtR;
    gemm(h0, cW1T, cb1, nullptr, tmpB, 512, 256, 256, 0, 0, 0, 0, nullptr, 0, 0, 256, nullptr);
    bf16_t* h1 = (bf16_t*)swR;
    ln_kernel<<<(unsigned)(Mg/4), 256, 0, stream>>>(tmpB, nullptr, cln1_s, cln1_b, h1, 1);

    // ---- h = silu(LN(h1 @ cW2 + cb2)) ----
    gemm(h1, cW2T, cb2, nullptr, tmpB, 256, 256, 256, 0, 0, 0, 0, nullptr, 0, 0, 256, nullptr);
    ln_kernel<<<(unsigned)(Mg/4), 256, 0, stream>>>(tmpB, nullptr, cln2_s, cln2_b, hG, 1);

    bf16_t* xz    = (bf16_t*)xzR;
    bf16_t* xc    = (bf16_t*)xcR;
    bf16_t* dt    = (bf16_t*)dtR;
    bf16_t* swcat = (bf16_t*)swR;

    for (int l = 0; l < L_; l++) {
      for (int dir = 0; dir < 2; dir++) {
        int ld = l*2 + dir;
        // xz = h @ Win (reversed read of h for dir=1)
        gemm(hG, m_inT + (size_t)ld*1024*256, nullptr, nullptr, xz,
             256, 1024, 1024, 0, 0, /*revA*/dir, 0, nullptr, 0, 0, 1024, nullptr);
        // xc = silu(dwconv(xi) + convB)
        conv_kernel<<<(unsigned)(Mg/4), 256, 0, stream>>>(
            xz, m_convK + (size_t)ld*512*4, m_convB + (size_t)ld*512, xc);
        // dt = softplus(xc @ dtW + dtB); epilogue also writes per-chunk col sums
        gemm(xc, m_dtWT + (size_t)ld*512*512, m_dtB + (size_t)ld*512, nullptr, dt,
             512, 512, 512, 0, /*act*/3, 0, 0, nullptr, 0, 0, 512, sums);
        // w = exp(-0.1*cumsum(dt)); y = xc * w * silu(z)   (in place over xc)
        y_kernel<<<(unsigned)(Bg*8), 256, 0, stream>>>(dt, xz, xc, sums);
        // swcat[:, dir*256:...] = y @ Wout (store reversed for dir=1)
        gemm(xc, m_outT + (size_t)ld*256*512, nullptr, nullptr, swcat,
             512, 256, 512, dir*256, 0, 0, /*revC*/dir, nullptr, 0, 0, 256, nullptr);
      }
      // combined = swcat @ proj_W + proj_b; h = LN(h + combined)
      bf16_t* tmpB2 = (bf16_t*)dtR;
      gemm(swcat, projT + (size_t)l*256*512, proj_b + (size_t)l*256, nullptr, tmpB2,
           512, 256, 256, 0, 0, 0, 0, nullptr, 0, 0, 256, nullptr);
      ln_kernel<<<(unsigned)(Mg/4), 256, 0, stream>>>(tmpB2, hG, norm_s + (size_t)l*256,
                                                      norm_b + (size_t)l*256, hG, 0);
    }

    // ---- logits + log_softmax ----
    float* logits = (float*)xzR;
    gemm(hG, outWT, outb, logits, nullptr, 256, 128, 41, 0, 0, 0, 0,
         nullptr, 0, 0, 41, nullptr);
    lsm_kernel<<<(unsigned)(Mg/4), 256, 0, stream>>>(logits, out + (size_t)b0 * T_ * 41);
  }
}